// Round 11
// baseline (346.119 us; speedup 1.0000x reference)
//
#include <hip/hip_runtime.h>
#include <hip/hip_bf16.h>
#include <cstdint>
#include <cstddef>

#define NGRAPH 64
#define NPG0   1024
#define NNODE  65536     // NGRAPH*NPG0
#define NEDGE  524288
#define EPG    8192      // NEDGE/NGRAPH
#define DIM    128
#define RCHUNK 16        // readout partial chunks per graph

// x / s buffers use PLANE layout per graph:
//   addr(g,p,v,c) = g*npg*128 + p*npg*16 + v*16 + c   (p=0..7, c=0..15)
// h_buf stays row-major [node][128].

typedef __attribute__((ext_vector_type(8))) short short8v;   // 8 bf16
typedef __attribute__((ext_vector_type(4))) float f32x4;

__device__ __forceinline__ unsigned bf16rne(float f) {
  unsigned u = __float_as_uint(f);
  return (u + 0x7FFFu + ((u >> 16) & 1u)) >> 16;
}

// ---------------- gather x = emb[node_idx] (plane layout out) -------------
__global__ __launch_bounds__(256) void k_gather(const float* __restrict__ emb,
    const int* __restrict__ nid, float* __restrict__ x)
{
  int tid = blockIdx.x * 256 + threadIdx.x;
  int i = tid >> 5, lane = tid & 31;
  int row = nid[i];
  float4 v = ((const float4*)(emb + (size_t)row * DIM))[lane];
  int g = i >> 10, vl = i & 1023;
  int p = lane >> 2, o = lane & 3;
  ((float4*)(x + (size_t)g * NPG0 * 128 + (size_t)p * NPG0 * 16 + (size_t)vl * 16))[o] = v;
}

// ---------------- 1/||pool_w|| ----------------
__global__ __launch_bounds__(64) void k_norm(const float* __restrict__ pw,
    float* __restrict__ inv_norm)
{
  int t = threadIdx.x;
  float a = pw[t], b = pw[t + 64];
  float v = a * a + b * b;
  for (int off = 32; off; off >>= 1) v += __shfl_xor(v, off);
  if (t == 0) *inv_norm = 1.0f / sqrtf(v);
}

// ------- pre-swizzle weights into MFMA B-fragment layout, bf16 hi/lo ------
__global__ __launch_bounds__(256) void k_prep_wfrag(
    const float* __restrict__ w1l, const float* __restrict__ w1r,
    const float* __restrict__ w2l, const float* __restrict__ w2r,
    short* __restrict__ whiF, short* __restrict__ wloF)
{
  int id = blockIdx.x * 256 + threadIdx.x;    // 0..65535 (2 sets x 32768)
  int set = id >> 15;
  int r = id & 32767;
  int j  = r & 7;
  int l  = (r >> 3) & 63;
  int nt = (r >> 9) & 7;
  int kk = r >> 12;
  int k = kk * 32 + ((l >> 4) & 3) * 8 + j;
  int n = nt * 16 + (l & 15);
  const float* wl = set ? w2l : w1l;
  const float* wr = set ? w2r : w1r;
  float w = (k < 128) ? wl[n * 128 + k] : wr[n * 128 + (k - 128)];
  unsigned hb = bf16rne(w);
  float hif = __uint_as_float(hb << 16);
  unsigned lb = bf16rne(w - hif);
  whiF[id] = (short)hb;
  wloF[id] = (short)lb;
}

// ---------------- stage-0 CSR build (LOCAL src ids in elist) --------------
__global__ __launch_bounds__(1024) void k_csr0(const int* __restrict__ ei,
    int* __restrict__ off_g, int* __restrict__ elist_g, float* __restrict__ c_out)
{
  __shared__ int cnt[1024];
  __shared__ int cur[1024];
  __shared__ int wsum[16];
  const int t = threadIdx.x, g = blockIdx.x;
  const int nodeBase = g * NPG0;
  const int e0 = g * EPG;
  cnt[t] = 0;
  __syncthreads();
  int sv8[8], dl8[8];
  #pragma unroll
  for (int i = 0; i < 8; ++i) {
    int e = e0 + t + i * 1024;
    sv8[i] = ei[e] - nodeBase;          // LOCAL
    dl8[i] = ei[NEDGE + e] - nodeBase;
    atomicAdd(&cnt[dl8[i]], 1);
  }
  __syncthreads();
  const int lane = t & 63, w = t >> 6;
  int cv = cnt[t];
  int x = cv;
  #pragma unroll
  for (int off = 1; off < 64; off <<= 1) {
    int y = __shfl_up(x, off);
    if (lane >= off) x += y;
  }
  if (lane == 63) wsum[w] = x;
  __syncthreads();
  if (t < 16) {
    int v = wsum[t];
    #pragma unroll
    for (int off2 = 1; off2 < 16; off2 <<= 1) {
      int y = __shfl_up(v, off2);
      if (t >= off2) v += y;
    }
    wsum[t] = v;
  }
  __syncthreads();
  int incl = x + (w ? wsum[w - 1] : 0);
  int excl = incl - cv;
  cur[t] = excl;
  int* offp = off_g + g * 1025;
  offp[t] = excl;
  if (t == 1023) offp[1024] = incl;
  c_out[nodeBase + t] = (float)cv;
  __syncthreads();
  int* elp = elist_g + g * EPG;
  #pragma unroll
  for (int i = 0; i < 8; ++i) {
    int pos = atomicAdd(&cur[dl8[i]], 1);
    elp[pos] = sv8[i];
  }
}

// ------- CSC aggregate: block = (plane, graph), x-plane staged in LDS -----
// Reads x ONCE (contiguous); per-edge reads hit LDS, not L2.
__global__ __launch_bounds__(512) void k_csc_agg(
    const int* __restrict__ off_g, const int* __restrict__ elist_g,
    const float* __restrict__ x, float* __restrict__ s, int npg)
{
  __shared__ float xs[16384];            // 64 KB: npg rows x 16 floats
  const int g = blockIdx.x & 63;
  const int p = blockIdx.x >> 6;         // 0..7
  const int t = threadIdx.x;
  const size_t pb = (size_t)g * npg * 128 + (size_t)p * npg * 16;
  const float4* xp4 = (const float4*)(x + pb);
  const int n4 = npg * 4;
  for (int i = t; i < n4; i += 512) ((float4*)xs)[i] = xp4[i];
  __syncthreads();
  const int grp = t >> 4, l16 = t & 15;  // 32 groups of 16 lanes
  const int per = (npg + 31) >> 5;
  const int v0 = grp * per;
  const int v1 = min(npg, v0 + per);
  const int* off = off_g + g * 1025;
  const int* el  = elist_g + g * EPG;
  float* sp = s + pb;
  for (int v = v0; v < v1; ++v) {
    int e = off[v], end = off[v + 1];
    float acc = 0.f;
    for (; e + 8 <= end; e += 8) {
      int s0 = el[e+0], s1 = el[e+1], s2 = el[e+2], s3 = el[e+3];
      int s4 = el[e+4], s5 = el[e+5], s6 = el[e+6], s7 = el[e+7];
      acc += ((xs[s0*16+l16] + xs[s1*16+l16]) + (xs[s2*16+l16] + xs[s3*16+l16]))
           + ((xs[s4*16+l16] + xs[s5*16+l16]) + (xs[s6*16+l16] + xs[s7*16+l16]));
    }
    for (; e + 2 <= end; e += 2) {
      int s0 = el[e], s1 = el[e+1];
      acc += xs[s0*16+l16] + xs[s1*16+l16];
    }
    if (e < end) acc += xs[el[e]*16 + l16];
    sp[v * 16 + l16] = acc;
  }
}

// ------- MFMA SAGE layer (plane inputs): h=relu([mean|x]@W+b), score ------
// blockIdx = slice*64 + g ; 64 rows/block, no LDS.
__global__ __launch_bounds__(256) void k_gemm_plane(
    const float* __restrict__ x, const float* __restrict__ s,
    const float* __restrict__ c, float* __restrict__ h_out,
    const short* __restrict__ whiF, const short* __restrict__ wloF,
    const float* __restrict__ bl, const float* __restrict__ pw,
    float* __restrict__ score, int npg)
{
  const int g = blockIdx.x & 63;
  const int slice = blockIdx.x >> 6;
  const int nodeBase = g * npg;
  const int vbase = slice * 64;
  const int t = threadIdx.x;
  const int wv = t >> 6, l = t & 63;
  const int lrow = l & 15, lk = l >> 4;
  const int rowb = wv * 16 + lrow;
  const int vclamp = min(vbase + rowb, npg - 1);
  const float invc = 1.0f / fmaxf(c[nodeBase + vclamp], 1.0f);
  const size_t gb = (size_t)g * npg * 128;
  const size_t pstride = (size_t)npg * 16;
  const int po = (lk & 1) * 8;
  const int ph = lk >> 1;
  const float* sbase = s + gb + (size_t)vclamp * 16 + po;
  const float* xbase = x + gb + (size_t)vclamp * 16 + po;
  f32x4 acc[8];
  #pragma unroll
  for (int nt = 0; nt < 8; ++nt) acc[nt] = (f32x4){0.f, 0.f, 0.f, 0.f};
  const short8v* bh = (const short8v*)whiF;
  const short8v* bo = (const short8v*)wloF;

  #pragma unroll
  for (int kk = 0; kk < 8; ++kk) {
    const float* ap = (kk < 4) ? (sbase + (size_t)(kk * 2 + ph) * pstride)
                               : (xbase + (size_t)((kk - 4) * 2 + ph) * pstride);
    float scl = (kk < 4) ? invc : 1.0f;
    float4 a0 = *(const float4*)ap;
    float4 a1 = *(const float4*)(ap + 4);
    float av[8] = { a0.x * scl, a0.y * scl, a0.z * scl, a0.w * scl,
                    a1.x * scl, a1.y * scl, a1.z * scl, a1.w * scl };
    short8v ahi, alo;
    #pragma unroll
    for (int j = 0; j < 8; ++j) {
      unsigned hb = bf16rne(av[j]);
      float hif = __uint_as_float(hb << 16);
      ahi[j] = (short)hb;
      alo[j] = (short)bf16rne(av[j] - hif);
    }
    #pragma unroll
    for (int nt = 0; nt < 8; ++nt) {
      int fi = (kk * 8 + nt) * 64 + l;
      short8v bhi = bh[fi];
      short8v blo = bo[fi];
      acc[nt] = __builtin_amdgcn_mfma_f32_16x16x32_bf16(ahi, bhi, acc[nt], 0, 0, 0);
      acc[nt] = __builtin_amdgcn_mfma_f32_16x16x32_bf16(alo, bhi, acc[nt], 0, 0, 0);
      acc[nt] = __builtin_amdgcn_mfma_f32_16x16x32_bf16(ahi, blo, acc[nt], 0, 0, 0);
    }
  }

  float sp0 = 0.f, sp1 = 0.f, sp2 = 0.f, sp3 = 0.f;
  const int mbv = vbase + wv * 16 + lk * 4;
  #pragma unroll
  for (int nt = 0; nt < 8; ++nt) {
    int col = nt * 16 + lrow;
    float bb = bl[col], pv = pw[col];
    float h0 = fmaxf(acc[nt][0] + bb, 0.f);
    float h1 = fmaxf(acc[nt][1] + bb, 0.f);
    float h2 = fmaxf(acc[nt][2] + bb, 0.f);
    float h3 = fmaxf(acc[nt][3] + bb, 0.f);
    if (mbv + 0 < npg) h_out[(size_t)(nodeBase + mbv + 0) * DIM + col] = h0;
    if (mbv + 1 < npg) h_out[(size_t)(nodeBase + mbv + 1) * DIM + col] = h1;
    if (mbv + 2 < npg) h_out[(size_t)(nodeBase + mbv + 2) * DIM + col] = h2;
    if (mbv + 3 < npg) h_out[(size_t)(nodeBase + mbv + 3) * DIM + col] = h3;
    sp0 += h0 * pv; sp1 += h1 * pv; sp2 += h2 * pv; sp3 += h3 * pv;
  }
  #pragma unroll
  for (int off = 1; off <= 8; off <<= 1) {
    sp0 += __shfl_xor(sp0, off);
    sp1 += __shfl_xor(sp1, off);
    sp2 += __shfl_xor(sp2, off);
    sp3 += __shfl_xor(sp3, off);
  }
  if (lrow == 0) {
    if (mbv + 0 < npg) score[nodeBase + mbv + 0] = sp0;
    if (mbv + 1 < npg) score[nodeBase + mbv + 1] = sp1;
    if (mbv + 2 < npg) score[nodeBase + mbv + 2] = sp2;
    if (mbv + 3 < npg) score[nodeBase + mbv + 3] = sp3;
  }
}

// ------- fused: bitonic top-k + relabel edges + build next CSR (local) ----
__global__ __launch_bounds__(1024) void k_topk_fused(
    const float* __restrict__ score, const float* __restrict__ inv_norm_p,
    int npg, int k, int* __restrict__ sel_pos, float* __restrict__ sel_scale,
    int build_next, int write_eout,
    const int* __restrict__ ein_src, const int* __restrict__ ein_dst,
    int* __restrict__ eout_src, int* __restrict__ eout_dst,
    int* __restrict__ off_g, int* __restrict__ elist_g, float* __restrict__ c_out)
{
  __shared__ float key[1024];
  __shared__ int   idxs[1024];
  __shared__ int   nid[1024];
  __shared__ int   cnt[1024];
  __shared__ int   cur[1024];
  __shared__ int   wsum[16];
  const int t = threadIdx.x, g = blockIdx.x;
  const int base = g * npg;
  key[t] = (t < npg) ? score[base + t] : -3.402823466e38f;
  idxs[t] = t;
  nid[t] = -1;
  cnt[t] = 0;
  __syncthreads();
  for (int size = 2; size <= 1024; size <<= 1) {
    for (int stride = size >> 1; stride > 0; stride >>= 1) {
      int p = t ^ stride;
      if (p > t) {
        float ka = key[t], kb = key[p];
        int ia = idxs[t], ib = idxs[p];
        bool a_first = (ka > kb) || (ka == kb && ia < ib);
        bool desc = ((t & size) == 0);
        if (desc ? !a_first : a_first) {
          key[t] = kb; key[p] = ka; idxs[t] = ib; idxs[p] = ia;
        }
      }
      __syncthreads();
    }
  }
  if (t < k) {
    float inv = *inv_norm_p;
    int local = idxs[t];
    nid[local] = t;
    sel_pos[g * k + t] = base + local;
    sel_scale[g * k + t] = tanhf(key[t] * inv);
  }
  if (!build_next) return;
  __syncthreads();
  const int e0 = g * EPG;
  const int newBase = g * k;
  int lns[8], lnd[8];
  #pragma unroll
  for (int i = 0; i < 8; ++i) {
    int e = e0 + t + i * 1024;
    int sv = ein_src[e];
    int ns = -1, nd = -1;
    if (sv >= 0) {
      int dv = ein_dst[e];
      ns = nid[sv - base];
      nd = nid[dv - base];
      if (ns < 0 || nd < 0) ns = -1;
    }
    lns[i] = ns; lnd[i] = nd;
    if (write_eout) {
      eout_src[e] = (ns >= 0) ? (newBase + ns) : -1;
      eout_dst[e] = (ns >= 0) ? (newBase + nd) : -1;
    }
    if (ns >= 0) atomicAdd(&cnt[nd], 1);
  }
  __syncthreads();
  const int lane = t & 63, w = t >> 6;
  int cv = cnt[t];
  int x = cv;
  #pragma unroll
  for (int off = 1; off < 64; off <<= 1) {
    int y = __shfl_up(x, off);
    if (lane >= off) x += y;
  }
  if (lane == 63) wsum[w] = x;
  __syncthreads();
  if (t < 16) {
    int v = wsum[t];
    #pragma unroll
    for (int off2 = 1; off2 < 16; off2 <<= 1) {
      int y = __shfl_up(v, off2);
      if (t >= off2) v += y;
    }
    wsum[t] = v;
  }
  __syncthreads();
  int incl = x + (w ? wsum[w - 1] : 0);
  int excl = incl - cv;
  cur[t] = excl;
  off_g[g * 1025 + t] = excl;
  if (t < k) c_out[newBase + t] = (float)cv;
  __syncthreads();
  int* elp = elist_g + g * EPG;
  #pragma unroll
  for (int i = 0; i < 8; ++i) {
    if (lns[i] >= 0) {
      int pos = atomicAdd(&cur[lnd[i]], 1);
      elp[pos] = lns[i];                 // LOCAL src id
    }
  }
}

// ------- fused pool + readout partial: reads h rows, writes x planes ------
__global__ __launch_bounds__(256) void k_pool_part(const float* __restrict__ h,
    const int* __restrict__ sel_pos, const float* __restrict__ sel_scale, int k,
    float* __restrict__ xo, float* __restrict__ pmax, float* __restrict__ psum)
{
  __shared__ float4 smx[256], ssm[256];
  const int b  = blockIdx.x >> 4;
  const int ch = blockIdx.x & (RCHUNK - 1);
  const int rpc = (k + RCHUNK - 1) / RCHUNK;
  const int r0 = ch * rpc;
  const int r1 = min(k, r0 + rpc);
  const int d4  = threadIdx.x & 31;
  const int sub = threadIdx.x >> 5;
  const int pl = d4 >> 2, o4 = d4 & 3;
  const size_t xgb = (size_t)b * k * 128;
  const float NEG = -3.402823466e38f;
  float4 mx = {NEG, NEG, NEG, NEG};
  float4 sm = {0.f, 0.f, 0.f, 0.f};
  for (int r = r0 + sub; r < r1; r += 8) {
    int j = b * k + r;
    float scv = sel_scale[j];
    float4 v = ((const float4*)(h + (size_t)sel_pos[j] * DIM))[d4];
    v.x *= scv; v.y *= scv; v.z *= scv; v.w *= scv;
    ((float4*)(xo + xgb + (size_t)pl * k * 16 + (size_t)r * 16))[o4] = v;
    mx.x = fmaxf(mx.x, v.x); mx.y = fmaxf(mx.y, v.y);
    mx.z = fmaxf(mx.z, v.z); mx.w = fmaxf(mx.w, v.w);
    sm.x += v.x; sm.y += v.y; sm.z += v.z; sm.w += v.w;
  }
  smx[threadIdx.x] = mx; ssm[threadIdx.x] = sm;
  __syncthreads();
  if (sub < 4) {
    #pragma unroll
    for (int step = 4; step >= 1; step >>= 1) {
      if (sub < step) {
        float4 m2 = smx[(sub + step) * 32 + d4];
        float4 s2 = ssm[(sub + step) * 32 + d4];
        mx = smx[sub * 32 + d4]; sm = ssm[sub * 32 + d4];
        mx.x = fmaxf(mx.x, m2.x); mx.y = fmaxf(mx.y, m2.y);
        mx.z = fmaxf(mx.z, m2.z); mx.w = fmaxf(mx.w, m2.w);
        sm.x += s2.x; sm.y += s2.y; sm.z += s2.z; sm.w += s2.w;
        smx[sub * 32 + d4] = mx; ssm[sub * 32 + d4] = sm;
      }
      __syncthreads();
    }
  }
  if (sub == 0) {
    int o = (b * RCHUNK + ch) * 32 + d4;
    ((float4*)pmax)[o] = smx[d4];
    ((float4*)psum)[o] = ssm[d4];
  }
}

// ------- readout stage B: combine partials, accumulate TRANSPOSED rdT -----
__global__ __launch_bounds__(128) void k_readout_final(const float* __restrict__ pmax,
    const float* __restrict__ psum, int k, float* __restrict__ rdT, int add)
{
  int b = blockIdx.x, d = threadIdx.x;
  float mx = -3.402823466e38f, sm = 0.f;
  #pragma unroll
  for (int c = 0; c < RCHUNK; ++c) {
    int o = (b * RCHUNK + c) * 128 + d;
    mx = fmaxf(mx, pmax[o]);
    sm += psum[o];
  }
  float mean = sm / (float)k;
  int omx = d * 64 + b;
  int omn = (128 + d) * 64 + b;
  if (add) { rdT[omx] += mx; rdT[omn] += mean; }
  else     { rdT[omx]  = mx; rdT[omn]  = mean; }
}

// ------- MLP fc1 + BN1 + relu: 16 blocks, lane=graph, wave=feature --------
__global__ __launch_bounds__(512) void k_mlp_fc1(const float* __restrict__ rdT,
    const float* __restrict__ fc1_w, const float* __restrict__ fc1_b,
    const float* __restrict__ g1, const float* __restrict__ be1,
    float* __restrict__ y1n)
{
  __shared__ float W[8 * 256];
  __shared__ float R[256 * 64];
  const int t = threadIdx.x, b = blockIdx.x;
  ((float4*)W)[t] = ((const float4*)(fc1_w + (size_t)b * 8 * 256))[t];
  #pragma unroll
  for (int i = 0; i < 8; ++i)
    ((float4*)R)[t + i * 512] = ((const float4*)rdT)[t + i * 512];
  __syncthreads();
  const int g = t & 63, w = t >> 6;
  const float* wrow = W + w * 256;
  float acc = 0.f;
  #pragma unroll 4
  for (int k = 0; k < 256; ++k) acc += R[k * 64 + g] * wrow[k];
  int f = b * 8 + w;
  float y = acc + fc1_b[f];
  float s = y, s2 = y * y;
  #pragma unroll
  for (int off = 32; off; off >>= 1) {
    s  += __shfl_xor(s,  off);
    s2 += __shfl_xor(s2, off);
  }
  float mu = s * 0.015625f;
  float var = s2 * 0.015625f - mu * mu;
  float inv = 1.0f / sqrtf(var + 1e-5f);
  y1n[f * 64 + g] = fmaxf((y - mu) * inv * g1[f] + be1[f], 0.f);
}

// ------- MLP rest: fc2 + BN2 + relu + lin + sigmoid (1 block) -------------
__global__ __launch_bounds__(1024) void k_mlp_rest(const float* __restrict__ y1n,
    const float* __restrict__ fc2_w, const float* __restrict__ fc2_b,
    const float* __restrict__ g2, const float* __restrict__ be2,
    const float* __restrict__ lin_w, const float* __restrict__ lin_b,
    float* __restrict__ out)
{
  __shared__ float W2[64 * 128];
  __shared__ float Y[128 * 64];
  __shared__ float part[16 * 64];
  const int t = threadIdx.x;
  #pragma unroll
  for (int i = 0; i < 2; ++i) {
    ((float4*)W2)[t + i * 1024] = ((const float4*)fc2_w)[t + i * 1024];
    ((float4*)Y) [t + i * 1024] = ((const float4*)y1n)[t + i * 1024];
  }
  __syncthreads();
  const int g = t & 63, w = t >> 6;
  float acc2[4] = {0.f, 0.f, 0.f, 0.f};
  const float* w20 = W2 + (w * 4 + 0) * 128;
  const float* w21 = W2 + (w * 4 + 1) * 128;
  const float* w22 = W2 + (w * 4 + 2) * 128;
  const float* w23 = W2 + (w * 4 + 3) * 128;
  #pragma unroll 4
  for (int k = 0; k < 128; ++k) {
    float yv = Y[k * 64 + g];
    acc2[0] += yv * w20[k];
    acc2[1] += yv * w21[k];
    acc2[2] += yv * w22[k];
    acc2[3] += yv * w23[k];
  }
  float pp = 0.f;
  #pragma unroll
  for (int j = 0; j < 4; ++j) {
    int m = w * 4 + j;
    float y = acc2[j] + fc2_b[m];
    float s = y, s2 = y * y;
    #pragma unroll
    for (int off = 32; off; off >>= 1) {
      s  += __shfl_xor(s,  off);
      s2 += __shfl_xor(s2, off);
    }
    float mu = s * 0.015625f;
    float var = s2 * 0.015625f - mu * mu;
    float inv = 1.0f / sqrtf(var + 1e-5f);
    float yn = fmaxf((y - mu) * inv * g2[m] + be2[m], 0.f);
    pp += yn * lin_w[m];
  }
  part[w * 64 + g] = pp;
  __syncthreads();
  if (w == 0) {
    float a = lin_b[0];
    #pragma unroll
    for (int c = 0; c < 16; ++c) a += part[c * 64 + g];
    out[g] = 1.0f / (1.0f + expf(-a));
  }
}

extern "C" void kernel_launch(void* const* d_in, const int* in_sizes, int n_in,
                              void* d_out, int out_size, void* d_ws, size_t ws_size,
                              hipStream_t stream) {
  const int*   node_idx = (const int*)  d_in[0];
  const int*   edge_idx = (const int*)  d_in[1];
  const float* emb      = (const float*)d_in[2];
  const float* w1l      = (const float*)d_in[3];
  const float* b1l      = (const float*)d_in[4];
  const float* w1r      = (const float*)d_in[5];
  const float* pool_w   = (const float*)d_in[6];
  const float* w2l      = (const float*)d_in[7];
  const float* b2l      = (const float*)d_in[8];
  const float* w2r      = (const float*)d_in[9];
  const float* fc1_w    = (const float*)d_in[10];
  const float* fc1_b    = (const float*)d_in[11];
  const float* bn1_g    = (const float*)d_in[12];
  const float* bn1_b    = (const float*)d_in[13];
  const float* fc2_w    = (const float*)d_in[14];
  const float* fc2_b    = (const float*)d_in[15];
  const float* bn2_g    = (const float*)d_in[16];
  const float* bn2_b    = (const float*)d_in[17];
  const float* lin_w    = (const float*)d_in[18];
  const float* lin_b    = (const float*)d_in[19];
  float* out = (float*)d_out;

  char* p = (char*)d_ws;
  auto alloc = [&](size_t bytes) -> void* {
    void* r = (void*)p;
    p += (bytes + 255) & ~(size_t)255;
    return r;
  };
  float* x_cur     = (float*)alloc((size_t)NNODE * DIM * 4);   // plane layout
  float* s_buf     = (float*)alloc((size_t)NNODE * DIM * 4);   // plane layout
  float* h_buf     = (float*)alloc((size_t)NNODE * DIM * 4);   // row-major
  float* c_buf     = (float*)alloc((size_t)NNODE * 4);
  float* score     = (float*)alloc((size_t)NNODE * 4);
  int*   sel_pos   = (int*)  alloc((size_t)NGRAPH * 820 * 4);
  float* sel_scale = (float*)alloc((size_t)NGRAPH * 820 * 4);
  int*   src_cur   = (int*)  alloc((size_t)NEDGE * 4);
  int*   dst_cur   = (int*)  alloc((size_t)NEDGE * 4);
  int*   off_g     = (int*)  alloc((size_t)NGRAPH * 1025 * 4);
  int*   elist_g   = (int*)  alloc((size_t)NGRAPH * EPG * 4);
  float* rdT       = (float*)alloc((size_t)256 * 64 * 4);
  short* whiF      = (short*)alloc((size_t)2 * 32768 * 2);
  short* wloF      = (short*)alloc((size_t)2 * 32768 * 2);
  float* y1n       = (float*)alloc((size_t)128 * 64 * 4);
  float* pmax      = (float*)alloc((size_t)NGRAPH * RCHUNK * 128 * 4);
  float* psum      = (float*)alloc((size_t)NGRAPH * RCHUNK * 128 * 4);
  float* inv_norm  = (float*)alloc(256);

  k_gather<<<NNODE * 32 / 256, 256, 0, stream>>>(emb, node_idx, x_cur);
  k_norm<<<1, 64, 0, stream>>>(pool_w, inv_norm);
  k_prep_wfrag<<<256, 256, 0, stream>>>(w1l, w1r, w2l, w2r, whiF, wloF);
  k_csr0<<<NGRAPH, 1024, 0, stream>>>(edge_idx, off_g, elist_g, c_buf);

  const int Ks[3] = {820, 656, 525};
  int npg = NPG0;
  for (int stage = 0; stage < 3; ++stage) {
    const short* whi_s = whiF + (stage ? 32768 : 0);
    const short* wlo_s = wloF + (stage ? 32768 : 0);
    const float* bl    = stage ? b2l : b1l;
    int k = Ks[stage];
    int slices = (npg + 63) >> 6;

    k_csc_agg<<<8 * NGRAPH, 512, 0, stream>>>(off_g, elist_g, x_cur, s_buf, npg);
    k_gemm_plane<<<slices * 64, 256, 0, stream>>>(x_cur, s_buf, c_buf, h_buf,
                                                  whi_s, wlo_s, bl, pool_w,
                                                  score, npg);
    const int* ein_s = (stage == 0) ? edge_idx          : src_cur;
    const int* ein_d = (stage == 0) ? (edge_idx + NEDGE) : dst_cur;
    k_topk_fused<<<NGRAPH, 1024, 0, stream>>>(score, inv_norm, npg, k,
        sel_pos, sel_scale,
        (stage < 2) ? 1 : 0, (stage == 0) ? 1 : 0,
        ein_s, ein_d, src_cur, dst_cur,
        off_g, elist_g, c_buf);
    k_pool_part<<<NGRAPH * RCHUNK, 256, 0, stream>>>(h_buf, sel_pos, sel_scale, k,
                                                     x_cur, pmax, psum);
    k_readout_final<<<NGRAPH, 128, 0, stream>>>(pmax, psum, k, rdT, stage == 0 ? 0 : 1);
    npg = k;
  }

  k_mlp_fc1<<<16, 512, 0, stream>>>(rdT, fc1_w, fc1_b, bn1_g, bn1_b, y1n);
  k_mlp_rest<<<1, 1024, 0, stream>>>(y1n, fc2_w, fc2_b, bn2_g, bn2_b,
                                     lin_w, lin_b, out);
}

// Round 12
// 281.784 us; speedup vs baseline: 1.2283x; 1.2283x over previous
//
#include <hip/hip_runtime.h>
#include <hip/hip_bf16.h>
#include <cstdint>
#include <cstddef>

#define NGRAPH 64
#define NPG0   1024
#define NNODE  65536     // NGRAPH*NPG0
#define NEDGE  524288
#define EPG    8192      // NEDGE/NGRAPH
#define DIM    128
#define RCHUNK 16        // readout partial chunks per graph

typedef __attribute__((ext_vector_type(8))) short short8v;   // 8 bf16
typedef __attribute__((ext_vector_type(4))) float f32x4;

__device__ __forceinline__ unsigned bf16rne(float f) {
  unsigned u = __float_as_uint(f);
  return (u + 0x7FFFu + ((u >> 16) & 1u)) >> 16;
}

// ---------------- gather x = emb[node_idx] ----------------
__global__ __launch_bounds__(256) void k_gather(const float* __restrict__ emb,
    const int* __restrict__ nid, float* __restrict__ x)
{
  int tid = blockIdx.x * 256 + threadIdx.x;
  int i = tid >> 5, lane = tid & 31;
  int row = nid[i];
  ((float4*)(x + (size_t)i * DIM))[lane] =
      ((const float4*)(emb + (size_t)row * DIM))[lane];
}

// ---------------- 1/||pool_w|| ----------------
__global__ __launch_bounds__(64) void k_norm(const float* __restrict__ pw,
    float* __restrict__ inv_norm)
{
  int t = threadIdx.x;
  float a = pw[t], b = pw[t + 64];
  float v = a * a + b * b;
  for (int off = 32; off; off >>= 1) v += __shfl_xor(v, off);
  if (t == 0) *inv_norm = 1.0f / sqrtf(v);
}

// ------- pre-swizzle weights into MFMA B-fragment layout, bf16 hi/lo ------
__global__ __launch_bounds__(256) void k_prep_wfrag(
    const float* __restrict__ w1l, const float* __restrict__ w1r,
    const float* __restrict__ w2l, const float* __restrict__ w2r,
    short* __restrict__ whiF, short* __restrict__ wloF)
{
  int id = blockIdx.x * 256 + threadIdx.x;    // 0..65535 (2 sets x 32768)
  int set = id >> 15;
  int r = id & 32767;
  int j  = r & 7;
  int l  = (r >> 3) & 63;
  int nt = (r >> 9) & 7;
  int kk = r >> 12;
  int k = kk * 32 + ((l >> 4) & 3) * 8 + j;
  int n = nt * 16 + (l & 15);
  const float* wl = set ? w2l : w1l;
  const float* wr = set ? w2r : w1r;
  float w = (k < 128) ? wl[n * 128 + k] : wr[n * 128 + (k - 128)];
  unsigned hb = bf16rne(w);
  float hif = __uint_as_float(hb << 16);
  unsigned lb = bf16rne(w - hif);
  whiF[id] = (short)hb;
  wloF[id] = (short)lb;
}

// ---------------- stage-0 CSR build straight from edge_idx ----------------
__global__ __launch_bounds__(1024) void k_csr0(const int* __restrict__ ei,
    int* __restrict__ off_g, int* __restrict__ elist_g, float* __restrict__ c_out)
{
  __shared__ int cnt[1024];
  __shared__ int cur[1024];
  __shared__ int wsum[16];
  const int t = threadIdx.x, g = blockIdx.x;
  const int nodeBase = g * NPG0;
  const int e0 = g * EPG;
  cnt[t] = 0;
  __syncthreads();
  int sv8[8], dl8[8];
  #pragma unroll
  for (int i = 0; i < 8; ++i) {
    int e = e0 + t + i * 1024;
    sv8[i] = ei[e];
    dl8[i] = ei[NEDGE + e] - nodeBase;
    atomicAdd(&cnt[dl8[i]], 1);
  }
  __syncthreads();
  const int lane = t & 63, w = t >> 6;
  int cv = cnt[t];
  int x = cv;
  #pragma unroll
  for (int off = 1; off < 64; off <<= 1) {
    int y = __shfl_up(x, off);
    if (lane >= off) x += y;
  }
  if (lane == 63) wsum[w] = x;
  __syncthreads();
  if (t < 16) {
    int v = wsum[t];
    #pragma unroll
    for (int off2 = 1; off2 < 16; off2 <<= 1) {
      int y = __shfl_up(v, off2);
      if (t >= off2) v += y;
    }
    wsum[t] = v;
  }
  __syncthreads();
  int incl = x + (w ? wsum[w - 1] : 0);
  int excl = incl - cv;
  cur[t] = excl;
  int* offp = off_g + g * 1025;
  offp[t] = excl;
  if (t == 1023) offp[1024] = incl;
  c_out[nodeBase + t] = (float)cv;
  __syncthreads();
  int* elp = elist_g + g * EPG;
  #pragma unroll
  for (int i = 0; i < 8; ++i) {
    int pos = atomicAdd(&cur[dl8[i]], 1);
    elp[pos] = sv8[i];
  }
}

// ------- FUSED aggregate + MFMA SAGE layer ---------------------------------
// One block = 64 consecutive ranked nodes of one graph.
// blockIdx = slice*64 + g  (XCD affinity: graph -> blockIdx%64 -> fixed XCD)
// Phase A: gather-sum neighbor rows into LDS (plain loads, XOR-swizzled).
// Phase B: h = relu([sA*invc | x] @ W + bl), write h + fused pool score.
__global__ __launch_bounds__(256) void k_agg_gemm(
    const int* __restrict__ off_g, const int* __restrict__ elist_g,
    const float* __restrict__ x, float* __restrict__ h_out,
    const short* __restrict__ whiF, const short* __restrict__ wloF,
    const float* __restrict__ bl, const float* __restrict__ pw,
    float* __restrict__ score, int npg)
{
  __shared__ float sA[64 * 128];   // 32 KB aggregate tile, float4-slot XOR swizzle
  __shared__ float cntA[64];
  const int g     = blockIdx.x & 63;
  const int slice = blockIdx.x >> 6;
  const int nodeBase = g * npg;
  const int vbase = slice * 64;
  const int t = threadIdx.x;
  float4* sA4 = (float4*)sA;

  // ---- phase A: gather-sum, 8 groups x 32 lanes, 8 rows each ----
  {
    const int gr = t >> 5, l32 = t & 31;
    const int* off = off_g + g * 1025;
    const int* el  = elist_g + g * EPG;
    #pragma unroll
    for (int i = 0; i < 8; ++i) {
      int vb = gr * 8 + i;
      int v = vbase + vb;
      float4 acc = {0.f, 0.f, 0.f, 0.f};
      int cn = 0;
      if (v < npg) {
        int e = off[v], end = off[v + 1];
        cn = end - e;
        for (; e + 8 <= end; e += 8) {
          int s0 = el[e+0], s1 = el[e+1], s2 = el[e+2], s3 = el[e+3];
          int s4 = el[e+4], s5 = el[e+5], s6 = el[e+6], s7 = el[e+7];
          float4 a0 = ((const float4*)(x + (size_t)s0 * DIM))[l32];
          float4 a1 = ((const float4*)(x + (size_t)s1 * DIM))[l32];
          float4 a2 = ((const float4*)(x + (size_t)s2 * DIM))[l32];
          float4 a3 = ((const float4*)(x + (size_t)s3 * DIM))[l32];
          float4 a4 = ((const float4*)(x + (size_t)s4 * DIM))[l32];
          float4 a5 = ((const float4*)(x + (size_t)s5 * DIM))[l32];
          float4 a6 = ((const float4*)(x + (size_t)s6 * DIM))[l32];
          float4 a7 = ((const float4*)(x + (size_t)s7 * DIM))[l32];
          acc.x += ((a0.x + a1.x) + (a2.x + a3.x)) + ((a4.x + a5.x) + (a6.x + a7.x));
          acc.y += ((a0.y + a1.y) + (a2.y + a3.y)) + ((a4.y + a5.y) + (a6.y + a7.y));
          acc.z += ((a0.z + a1.z) + (a2.z + a3.z)) + ((a4.z + a5.z) + (a6.z + a7.z));
          acc.w += ((a0.w + a1.w) + (a2.w + a3.w)) + ((a4.w + a5.w) + (a6.w + a7.w));
        }
        if (e + 4 <= end) {
          int s0 = el[e+0], s1 = el[e+1], s2 = el[e+2], s3 = el[e+3];
          float4 a0 = ((const float4*)(x + (size_t)s0 * DIM))[l32];
          float4 a1 = ((const float4*)(x + (size_t)s1 * DIM))[l32];
          float4 a2 = ((const float4*)(x + (size_t)s2 * DIM))[l32];
          float4 a3 = ((const float4*)(x + (size_t)s3 * DIM))[l32];
          acc.x += (a0.x + a1.x) + (a2.x + a3.x);
          acc.y += (a0.y + a1.y) + (a2.y + a3.y);
          acc.z += (a0.z + a1.z) + (a2.z + a3.z);
          acc.w += (a0.w + a1.w) + (a2.w + a3.w);
          e += 4;
        }
        for (; e < end; ++e) {
          float4 a = ((const float4*)(x + (size_t)el[e] * DIM))[l32];
          acc.x += a.x; acc.y += a.y; acc.z += a.z; acc.w += a.w;
        }
      }
      sA4[vb * 32 + (l32 ^ (vb & 7))] = acc;   // swizzled write (permutation)
      if (l32 == 0) cntA[vb] = (float)cn;
    }
  }
  __syncthreads();

  // ---- phase B: MFMA GEMM ----
  const int wv = t >> 6, l = t & 63;
  const int lrow = l & 15, lk = l >> 4;      // lk 0..3
  const int rb = wv * 16;                    // row-in-block base for A
  const int rowb = rb + lrow;                // A row in block
  const int rsw = rowb & 7;                  // swizzle key
  const int rowg = nodeBase + min(vbase + rowb, npg - 1);  // clamped global
  const float invc = 1.0f / fmaxf(cntA[rowb], 1.0f);
  f32x4 acc[8];
  #pragma unroll
  for (int nt = 0; nt < 8; ++nt) acc[nt] = (f32x4){0.f, 0.f, 0.f, 0.f};
  const float4* sArow = sA4 + rowb * 32;
  const float* xrow = x + (size_t)rowg * DIM + lk * 8;     // global
  const short8v* bh = (const short8v*)whiF;
  const short8v* bo = (const short8v*)wloF;

  #pragma unroll
  for (int kk = 0; kk < 8; ++kk) {
    float av[8];
    if (kk < 4) {
      int sbase = kk * 8 + lk * 2;
      float4 a0 = sArow[(sbase + 0) ^ rsw];
      float4 a1 = sArow[(sbase + 1) ^ rsw];
      av[0] = a0.x * invc; av[1] = a0.y * invc;
      av[2] = a0.z * invc; av[3] = a0.w * invc;
      av[4] = a1.x * invc; av[5] = a1.y * invc;
      av[6] = a1.z * invc; av[7] = a1.w * invc;
    } else {
      float4 a0 = *(const float4*)(xrow + (kk - 4) * 32);
      float4 a1 = *(const float4*)(xrow + (kk - 4) * 32 + 4);
      av[0] = a0.x; av[1] = a0.y; av[2] = a0.z; av[3] = a0.w;
      av[4] = a1.x; av[5] = a1.y; av[6] = a1.z; av[7] = a1.w;
    }
    short8v ahi, alo;
    #pragma unroll
    for (int j = 0; j < 8; ++j) {
      unsigned hb = bf16rne(av[j]);
      float hif = __uint_as_float(hb << 16);
      ahi[j] = (short)hb;
      alo[j] = (short)bf16rne(av[j] - hif);
    }
    #pragma unroll
    for (int nt = 0; nt < 8; ++nt) {
      int fi = (kk * 8 + nt) * 64 + l;
      short8v bhi = bh[fi];
      short8v blo = bo[fi];
      acc[nt] = __builtin_amdgcn_mfma_f32_16x16x32_bf16(ahi, bhi, acc[nt], 0, 0, 0);
      acc[nt] = __builtin_amdgcn_mfma_f32_16x16x32_bf16(alo, bhi, acc[nt], 0, 0, 0);
      acc[nt] = __builtin_amdgcn_mfma_f32_16x16x32_bf16(ahi, blo, acc[nt], 0, 0, 0);
    }
  }

  // epilogue: bias + relu + guarded store + fused pool-score partials
  float sp0 = 0.f, sp1 = 0.f, sp2 = 0.f, sp3 = 0.f;
  const int mbv = vbase + rb + lk * 4;       // in-graph row base for C
  #pragma unroll
  for (int nt = 0; nt < 8; ++nt) {
    int col = nt * 16 + lrow;
    float bb = bl[col], pv = pw[col];
    float h0 = fmaxf(acc[nt][0] + bb, 0.f);
    float h1 = fmaxf(acc[nt][1] + bb, 0.f);
    float h2 = fmaxf(acc[nt][2] + bb, 0.f);
    float h3 = fmaxf(acc[nt][3] + bb, 0.f);
    if (mbv + 0 < npg) h_out[(size_t)(nodeBase + mbv + 0) * DIM + col] = h0;
    if (mbv + 1 < npg) h_out[(size_t)(nodeBase + mbv + 1) * DIM + col] = h1;
    if (mbv + 2 < npg) h_out[(size_t)(nodeBase + mbv + 2) * DIM + col] = h2;
    if (mbv + 3 < npg) h_out[(size_t)(nodeBase + mbv + 3) * DIM + col] = h3;
    sp0 += h0 * pv; sp1 += h1 * pv; sp2 += h2 * pv; sp3 += h3 * pv;
  }
  #pragma unroll
  for (int off = 1; off <= 8; off <<= 1) {
    sp0 += __shfl_xor(sp0, off);
    sp1 += __shfl_xor(sp1, off);
    sp2 += __shfl_xor(sp2, off);
    sp3 += __shfl_xor(sp3, off);
  }
  if (lrow == 0) {
    if (mbv + 0 < npg) score[nodeBase + mbv + 0] = sp0;
    if (mbv + 1 < npg) score[nodeBase + mbv + 1] = sp1;
    if (mbv + 2 < npg) score[nodeBase + mbv + 2] = sp2;
    if (mbv + 3 < npg) score[nodeBase + mbv + 3] = sp3;
  }
}

// ------- fused: bitonic top-k + relabel edges + build next-stage CSR ------
__global__ __launch_bounds__(1024) void k_topk_fused(
    const float* __restrict__ score, const float* __restrict__ inv_norm_p,
    int npg, int k, int* __restrict__ sel_pos, float* __restrict__ sel_scale,
    int build_next, int write_eout,
    const int* __restrict__ ein_src, const int* __restrict__ ein_dst,
    int* __restrict__ eout_src, int* __restrict__ eout_dst,
    int* __restrict__ off_g, int* __restrict__ elist_g, float* __restrict__ c_out)
{
  __shared__ float key[1024];
  __shared__ int   idxs[1024];
  __shared__ int   nid[1024];
  __shared__ int   cnt[1024];
  __shared__ int   cur[1024];
  __shared__ int   wsum[16];
  const int t = threadIdx.x, g = blockIdx.x;
  const int base = g * npg;
  key[t] = (t < npg) ? score[base + t] : -3.402823466e38f;
  idxs[t] = t;
  nid[t] = -1;
  cnt[t] = 0;
  __syncthreads();
  for (int size = 2; size <= 1024; size <<= 1) {
    for (int stride = size >> 1; stride > 0; stride >>= 1) {
      int p = t ^ stride;
      if (p > t) {
        float ka = key[t], kb = key[p];
        int ia = idxs[t], ib = idxs[p];
        bool a_first = (ka > kb) || (ka == kb && ia < ib);
        bool desc = ((t & size) == 0);
        if (desc ? !a_first : a_first) {
          key[t] = kb; key[p] = ka; idxs[t] = ib; idxs[p] = ia;
        }
      }
      __syncthreads();
    }
  }
  if (t < k) {
    float inv = *inv_norm_p;
    int local = idxs[t];
    nid[local] = t;
    sel_pos[g * k + t] = base + local;
    sel_scale[g * k + t] = tanhf(key[t] * inv);
  }
  if (!build_next) return;
  __syncthreads();
  const int e0 = g * EPG;
  const int newBase = g * k;
  int lns[8], lnd[8];
  #pragma unroll
  for (int i = 0; i < 8; ++i) {
    int e = e0 + t + i * 1024;
    int sv = ein_src[e];
    int ns = -1, nd = -1;
    if (sv >= 0) {
      int dv = ein_dst[e];
      ns = nid[sv - base];
      nd = nid[dv - base];
      if (ns < 0 || nd < 0) ns = -1;
    }
    lns[i] = ns; lnd[i] = nd;
    if (write_eout) {
      eout_src[e] = (ns >= 0) ? (newBase + ns) : -1;
      eout_dst[e] = (ns >= 0) ? (newBase + nd) : -1;
    }
    if (ns >= 0) atomicAdd(&cnt[nd], 1);
  }
  __syncthreads();
  const int lane = t & 63, w = t >> 6;
  int cv = cnt[t];
  int x = cv;
  #pragma unroll
  for (int off = 1; off < 64; off <<= 1) {
    int y = __shfl_up(x, off);
    if (lane >= off) x += y;
  }
  if (lane == 63) wsum[w] = x;
  __syncthreads();
  if (t < 16) {
    int v = wsum[t];
    #pragma unroll
    for (int off2 = 1; off2 < 16; off2 <<= 1) {
      int y = __shfl_up(v, off2);
      if (t >= off2) v += y;
    }
    wsum[t] = v;
  }
  __syncthreads();
  int incl = x + (w ? wsum[w - 1] : 0);
  int excl = incl - cv;
  cur[t] = excl;
  off_g[g * 1025 + t] = excl;      // t>=k all hold total, so off[k] is correct
  if (t < k) c_out[newBase + t] = (float)cv;
  __syncthreads();
  int* elp = elist_g + g * EPG;
  #pragma unroll
  for (int i = 0; i < 8; ++i) {
    if (lns[i] >= 0) {
      int pos = atomicAdd(&cur[lnd[i]], 1);
      elp[pos] = newBase + lns[i];
    }
  }
}

// ------- fused pool + readout partial (float4 rows): block=(graph,chunk) --
__global__ __launch_bounds__(256) void k_pool_part(const float* __restrict__ h,
    const int* __restrict__ sel_pos, const float* __restrict__ sel_scale, int k,
    float* __restrict__ xo, float* __restrict__ pmax, float* __restrict__ psum)
{
  __shared__ float4 smx[256], ssm[256];
  const int b  = blockIdx.x >> 4;
  const int ch = blockIdx.x & (RCHUNK - 1);
  const int rpc = (k + RCHUNK - 1) / RCHUNK;
  const int r0 = ch * rpc;
  const int r1 = min(k, r0 + rpc);
  const int d4  = threadIdx.x & 31;      // float4 index in row
  const int sub = threadIdx.x >> 5;      // 8 rows in flight
  const float NEG = -3.402823466e38f;
  float4 mx = {NEG, NEG, NEG, NEG};
  float4 sm = {0.f, 0.f, 0.f, 0.f};
  for (int r = r0 + sub; r < r1; r += 8) {
    int j = b * k + r;
    float scv = sel_scale[j];
    float4 v = ((const float4*)(h + (size_t)sel_pos[j] * DIM))[d4];
    v.x *= scv; v.y *= scv; v.z *= scv; v.w *= scv;
    ((float4*)(xo + (size_t)j * DIM))[d4] = v;
    mx.x = fmaxf(mx.x, v.x); mx.y = fmaxf(mx.y, v.y);
    mx.z = fmaxf(mx.z, v.z); mx.w = fmaxf(mx.w, v.w);
    sm.x += v.x; sm.y += v.y; sm.z += v.z; sm.w += v.w;
  }
  smx[threadIdx.x] = mx; ssm[threadIdx.x] = sm;
  __syncthreads();
  if (sub < 4) {  // reduce 8 -> 1 via tree in LDS (3 steps)
    #pragma unroll
    for (int step = 4; step >= 1; step >>= 1) {
      if (sub < step) {
        float4 m2 = smx[(sub + step) * 32 + d4];
        float4 s2 = ssm[(sub + step) * 32 + d4];
        mx = smx[sub * 32 + d4]; sm = ssm[sub * 32 + d4];
        mx.x = fmaxf(mx.x, m2.x); mx.y = fmaxf(mx.y, m2.y);
        mx.z = fmaxf(mx.z, m2.z); mx.w = fmaxf(mx.w, m2.w);
        sm.x += s2.x; sm.y += s2.y; sm.z += s2.z; sm.w += s2.w;
        smx[sub * 32 + d4] = mx; ssm[sub * 32 + d4] = sm;
      }
      __syncthreads();
    }
  }
  if (sub == 0) {
    int o = (b * RCHUNK + ch) * 32 + d4;
    ((float4*)pmax)[o] = smx[d4];
    ((float4*)psum)[o] = ssm[d4];
  }
}

// ------- readout stage B: combine partials, accumulate TRANSPOSED rdT -----
__global__ __launch_bounds__(128) void k_readout_final(const float* __restrict__ pmax,
    const float* __restrict__ psum, int k, float* __restrict__ rdT, int add)
{
  int b = blockIdx.x, d = threadIdx.x;
  float mx = -3.402823466e38f, sm = 0.f;
  #pragma unroll
  for (int c = 0; c < RCHUNK; ++c) {
    int o = (b * RCHUNK + c) * 128 + d;
    mx = fmaxf(mx, pmax[o]);
    sm += psum[o];
  }
  float mean = sm / (float)k;
  int omx = d * 64 + b;
  int omn = (128 + d) * 64 + b;
  if (add) { rdT[omx] += mx; rdT[omn] += mean; }
  else     { rdT[omx]  = mx; rdT[omn]  = mean; }
}

// ------- MLP fc1 + BN1 + relu: 16 blocks, lane=graph, wave=feature --------
__global__ __launch_bounds__(512) void k_mlp_fc1(const float* __restrict__ rdT,
    const float* __restrict__ fc1_w, const float* __restrict__ fc1_b,
    const float* __restrict__ g1, const float* __restrict__ be1,
    float* __restrict__ y1n)
{
  __shared__ float W[8 * 256];       // 8 KB
  __shared__ float R[256 * 64];      // 64 KB
  const int t = threadIdx.x, b = blockIdx.x;
  ((float4*)W)[t] = ((const float4*)(fc1_w + (size_t)b * 8 * 256))[t];
  #pragma unroll
  for (int i = 0; i < 8; ++i)
    ((float4*)R)[t + i * 512] = ((const float4*)rdT)[t + i * 512];
  __syncthreads();
  const int g = t & 63, w = t >> 6;  // 8 waves, one feature each
  const float* wrow = W + w * 256;
  float acc = 0.f;
  #pragma unroll 4
  for (int k = 0; k < 256; ++k) acc += R[k * 64 + g] * wrow[k];
  int f = b * 8 + w;
  float y = acc + fc1_b[f];
  float s = y, s2 = y * y;
  #pragma unroll
  for (int off = 32; off; off >>= 1) {
    s  += __shfl_xor(s,  off);
    s2 += __shfl_xor(s2, off);
  }
  float mu = s * 0.015625f;
  float var = s2 * 0.015625f - mu * mu;
  float inv = 1.0f / sqrtf(var + 1e-5f);
  y1n[f * 64 + g] = fmaxf((y - mu) * inv * g1[f] + be1[f], 0.f);
}

// ------- MLP rest: fc2 + BN2 + relu + lin + sigmoid (1 block) -------------
__global__ __launch_bounds__(1024) void k_mlp_rest(const float* __restrict__ y1n,
    const float* __restrict__ fc2_w, const float* __restrict__ fc2_b,
    const float* __restrict__ g2, const float* __restrict__ be2,
    const float* __restrict__ lin_w, const float* __restrict__ lin_b,
    float* __restrict__ out)
{
  __shared__ float W2[64 * 128];     // 32 KB
  __shared__ float Y[128 * 64];      // 32 KB
  __shared__ float part[16 * 64];    // 4 KB
  const int t = threadIdx.x;
  #pragma unroll
  for (int i = 0; i < 2; ++i) {
    ((float4*)W2)[t + i * 1024] = ((const float4*)fc2_w)[t + i * 1024];
    ((float4*)Y) [t + i * 1024] = ((const float4*)y1n)[t + i * 1024];
  }
  __syncthreads();
  const int g = t & 63, w = t >> 6;  // 16 waves x 4 features
  float acc2[4] = {0.f, 0.f, 0.f, 0.f};
  const float* w20 = W2 + (w * 4 + 0) * 128;
  const float* w21 = W2 + (w * 4 + 1) * 128;
  const float* w22 = W2 + (w * 4 + 2) * 128;
  const float* w23 = W2 + (w * 4 + 3) * 128;
  #pragma unroll 4
  for (int k = 0; k < 128; ++k) {
    float yv = Y[k * 64 + g];
    acc2[0] += yv * w20[k];
    acc2[1] += yv * w21[k];
    acc2[2] += yv * w22[k];
    acc2[3] += yv * w23[k];
  }
  float pp = 0.f;
  #pragma unroll
  for (int j = 0; j < 4; ++j) {
    int m = w * 4 + j;
    float y = acc2[j] + fc2_b[m];
    float s = y, s2 = y * y;
    #pragma unroll
    for (int off = 32; off; off >>= 1) {
      s  += __shfl_xor(s,  off);
      s2 += __shfl_xor(s2, off);
    }
    float mu = s * 0.015625f;
    float var = s2 * 0.015625f - mu * mu;
    float inv = 1.0f / sqrtf(var + 1e-5f);
    float yn = fmaxf((y - mu) * inv * g2[m] + be2[m], 0.f);
    pp += yn * lin_w[m];
  }
  part[w * 64 + g] = pp;
  __syncthreads();
  if (w == 0) {
    float a = lin_b[0];
    #pragma unroll
    for (int c = 0; c < 16; ++c) a += part[c * 64 + g];
    out[g] = 1.0f / (1.0f + expf(-a));
  }
}

extern "C" void kernel_launch(void* const* d_in, const int* in_sizes, int n_in,
                              void* d_out, int out_size, void* d_ws, size_t ws_size,
                              hipStream_t stream) {
  const int*   node_idx = (const int*)  d_in[0];
  const int*   edge_idx = (const int*)  d_in[1];
  const float* emb      = (const float*)d_in[2];
  const float* w1l      = (const float*)d_in[3];
  const float* b1l      = (const float*)d_in[4];
  const float* w1r      = (const float*)d_in[5];
  const float* pool_w   = (const float*)d_in[6];
  const float* w2l      = (const float*)d_in[7];
  const float* b2l      = (const float*)d_in[8];
  const float* w2r      = (const float*)d_in[9];
  const float* fc1_w    = (const float*)d_in[10];
  const float* fc1_b    = (const float*)d_in[11];
  const float* bn1_g    = (const float*)d_in[12];
  const float* bn1_b    = (const float*)d_in[13];
  const float* fc2_w    = (const float*)d_in[14];
  const float* fc2_b    = (const float*)d_in[15];
  const float* bn2_g    = (const float*)d_in[16];
  const float* bn2_b    = (const float*)d_in[17];
  const float* lin_w    = (const float*)d_in[18];
  const float* lin_b    = (const float*)d_in[19];
  float* out = (float*)d_out;

  char* p = (char*)d_ws;
  auto alloc = [&](size_t bytes) -> void* {
    void* r = (void*)p;
    p += (bytes + 255) & ~(size_t)255;
    return r;
  };
  float* x_cur     = (float*)alloc((size_t)NNODE * DIM * 4);
  float* s_buf     = (float*)alloc((size_t)NNODE * DIM * 4);
  float* c_buf     = (float*)alloc((size_t)NNODE * 4);
  float* score     = (float*)alloc((size_t)NNODE * 4);
  int*   sel_pos   = (int*)  alloc((size_t)NGRAPH * 820 * 4);
  float* sel_scale = (float*)alloc((size_t)NGRAPH * 820 * 4);
  int*   src_cur   = (int*)  alloc((size_t)NEDGE * 4);
  int*   dst_cur   = (int*)  alloc((size_t)NEDGE * 4);
  int*   off_g     = (int*)  alloc((size_t)NGRAPH * 1025 * 4);
  int*   elist_g   = (int*)  alloc((size_t)NGRAPH * EPG * 4);
  float* rdT       = (float*)alloc((size_t)256 * 64 * 4);
  short* whiF      = (short*)alloc((size_t)2 * 32768 * 2);
  short* wloF      = (short*)alloc((size_t)2 * 32768 * 2);
  float* y1n       = (float*)alloc((size_t)128 * 64 * 4);
  float* pmax      = (float*)alloc((size_t)NGRAPH * RCHUNK * 128 * 4);
  float* psum      = (float*)alloc((size_t)NGRAPH * RCHUNK * 128 * 4);
  float* inv_norm  = (float*)alloc(256);

  k_gather<<<NNODE * 32 / 256, 256, 0, stream>>>(emb, node_idx, x_cur);
  k_norm<<<1, 64, 0, stream>>>(pool_w, inv_norm);
  k_prep_wfrag<<<256, 256, 0, stream>>>(w1l, w1r, w2l, w2r, whiF, wloF);
  k_csr0<<<NGRAPH, 1024, 0, stream>>>(edge_idx, off_g, elist_g, c_buf);

  const int Ks[3] = {820, 656, 525};
  int npg = NPG0;
  for (int stage = 0; stage < 3; ++stage) {
    const short* whi_s = whiF + (stage ? 32768 : 0);
    const short* wlo_s = wloF + (stage ? 32768 : 0);
    const float* bl    = stage ? b2l : b1l;
    int k = Ks[stage];
    int slices = (npg + 63) >> 6;

    k_agg_gemm<<<slices * 64, 256, 0, stream>>>(off_g, elist_g, x_cur, s_buf,
                                                whi_s, wlo_s, bl, pool_w,
                                                score, npg);
    const int* ein_s = (stage == 0) ? edge_idx          : src_cur;
    const int* ein_d = (stage == 0) ? (edge_idx + NEDGE) : dst_cur;
    k_topk_fused<<<NGRAPH, 1024, 0, stream>>>(score, inv_norm, npg, k,
        sel_pos, sel_scale,
        (stage < 2) ? 1 : 0, (stage == 0) ? 1 : 0,
        ein_s, ein_d, src_cur, dst_cur,
        off_g, elist_g, c_buf);
    k_pool_part<<<NGRAPH * RCHUNK, 256, 0, stream>>>(s_buf, sel_pos, sel_scale, k,
                                                     x_cur, pmax, psum);
    k_readout_final<<<NGRAPH, 128, 0, stream>>>(pmax, psum, k, rdT, stage == 0 ? 0 : 1);
    npg = k;
  }

  k_mlp_fc1<<<16, 512, 0, stream>>>(rdT, fc1_w, fc1_b, bn1_g, bn1_b, y1n);
  k_mlp_rest<<<1, 1024, 0, stream>>>(y1n, fc2_w, fc2_b, bn2_g, bn2_b,
                                     lin_w, lin_b, out);
}

// Round 13
// 265.454 us; speedup vs baseline: 1.3039x; 1.0615x over previous
//
#include <hip/hip_runtime.h>
#include <hip/hip_bf16.h>
#include <cstdint>
#include <cstddef>

#define NGRAPH 64
#define NPG0   1024
#define NNODE  65536     // NGRAPH*NPG0
#define NEDGE  524288
#define EPG    8192      // NEDGE/NGRAPH
#define DIM    128
#define RCHUNK 16        // readout partial chunks per graph
#define PSTRIDE ((size_t)NGRAPH * RCHUNK * 128)

typedef __attribute__((ext_vector_type(8))) short short8v;   // 8 bf16
typedef __attribute__((ext_vector_type(4))) float f32x4;

__device__ __forceinline__ unsigned bf16rne(float f) {
  unsigned u = __float_as_uint(f);
  return (u + 0x7FFFu + ((u >> 16) & 1u)) >> 16;
}

// drain remaining edges of one row (4-batch then singles)
__device__ __forceinline__ void drain_row(const int* __restrict__ el,
    const float* __restrict__ x, int l32, int e, int end, float4& acc)
{
  for (; e + 4 <= end; e += 4) {
    int s0 = el[e], s1 = el[e+1], s2 = el[e+2], s3 = el[e+3];
    float4 a0 = ((const float4*)(x + (size_t)s0 * DIM))[l32];
    float4 a1 = ((const float4*)(x + (size_t)s1 * DIM))[l32];
    float4 a2 = ((const float4*)(x + (size_t)s2 * DIM))[l32];
    float4 a3 = ((const float4*)(x + (size_t)s3 * DIM))[l32];
    acc.x += (a0.x + a1.x) + (a2.x + a3.x);
    acc.y += (a0.y + a1.y) + (a2.y + a3.y);
    acc.z += (a0.z + a1.z) + (a2.z + a3.z);
    acc.w += (a0.w + a1.w) + (a2.w + a3.w);
  }
  for (; e < end; ++e) {
    float4 a = ((const float4*)(x + (size_t)el[e] * DIM))[l32];
    acc.x += a.x; acc.y += a.y; acc.z += a.z; acc.w += a.w;
  }
}

// ---------------- gather x = emb[node_idx] ----------------
__global__ __launch_bounds__(256) void k_gather(const float* __restrict__ emb,
    const int* __restrict__ nid, float* __restrict__ x)
{
  int tid = blockIdx.x * 256 + threadIdx.x;
  int i = tid >> 5, lane = tid & 31;
  int row = nid[i];
  ((float4*)(x + (size_t)i * DIM))[lane] =
      ((const float4*)(emb + (size_t)row * DIM))[lane];
}

// ---------------- 1/||pool_w|| ----------------
__global__ __launch_bounds__(64) void k_norm(const float* __restrict__ pw,
    float* __restrict__ inv_norm)
{
  int t = threadIdx.x;
  float a = pw[t], b = pw[t + 64];
  float v = a * a + b * b;
  for (int off = 32; off; off >>= 1) v += __shfl_xor(v, off);
  if (t == 0) *inv_norm = 1.0f / sqrtf(v);
}

// ------- pre-swizzle weights into MFMA B-fragment layout, bf16 hi/lo ------
__global__ __launch_bounds__(256) void k_prep_wfrag(
    const float* __restrict__ w1l, const float* __restrict__ w1r,
    const float* __restrict__ w2l, const float* __restrict__ w2r,
    short* __restrict__ whiF, short* __restrict__ wloF)
{
  int id = blockIdx.x * 256 + threadIdx.x;    // 0..65535 (2 sets x 32768)
  int set = id >> 15;
  int r = id & 32767;
  int j  = r & 7;
  int l  = (r >> 3) & 63;
  int nt = (r >> 9) & 7;
  int kk = r >> 12;
  int k = kk * 32 + ((l >> 4) & 3) * 8 + j;
  int n = nt * 16 + (l & 15);
  const float* wl = set ? w2l : w1l;
  const float* wr = set ? w2r : w1r;
  float w = (k < 128) ? wl[n * 128 + k] : wr[n * 128 + (k - 128)];
  unsigned hb = bf16rne(w);
  float hif = __uint_as_float(hb << 16);
  unsigned lb = bf16rne(w - hif);
  whiF[id] = (short)hb;
  wloF[id] = (short)lb;
}

// ---------------- stage-0 CSR build straight from edge_idx ----------------
__global__ __launch_bounds__(1024) void k_csr0(const int* __restrict__ ei,
    int* __restrict__ off_g, int* __restrict__ elist_g, float* __restrict__ c_out)
{
  __shared__ int cnt[1024];
  __shared__ int cur[1024];
  __shared__ int wsum[16];
  const int t = threadIdx.x, g = blockIdx.x;
  const int nodeBase = g * NPG0;
  const int e0 = g * EPG;
  cnt[t] = 0;
  __syncthreads();
  int sv8[8], dl8[8];
  #pragma unroll
  for (int i = 0; i < 8; ++i) {
    int e = e0 + t + i * 1024;
    sv8[i] = ei[e];
    dl8[i] = ei[NEDGE + e] - nodeBase;
    atomicAdd(&cnt[dl8[i]], 1);
  }
  __syncthreads();
  const int lane = t & 63, w = t >> 6;
  int cv = cnt[t];
  int x = cv;
  #pragma unroll
  for (int off = 1; off < 64; off <<= 1) {
    int y = __shfl_up(x, off);
    if (lane >= off) x += y;
  }
  if (lane == 63) wsum[w] = x;
  __syncthreads();
  if (t < 16) {
    int v = wsum[t];
    #pragma unroll
    for (int off2 = 1; off2 < 16; off2 <<= 1) {
      int y = __shfl_up(v, off2);
      if (t >= off2) v += y;
    }
    wsum[t] = v;
  }
  __syncthreads();
  int incl = x + (w ? wsum[w - 1] : 0);
  int excl = incl - cv;
  cur[t] = excl;
  int* offp = off_g + g * 1025;
  offp[t] = excl;
  if (t == 1023) offp[1024] = incl;
  c_out[nodeBase + t] = (float)cv;
  __syncthreads();
  int* elp = elist_g + g * EPG;
  #pragma unroll
  for (int i = 0; i < 8; ++i) {
    int pos = atomicAdd(&cur[dl8[i]], 1);
    elp[pos] = sv8[i];
  }
}

// ------- FUSED aggregate + MFMA SAGE layer ---------------------------------
// Phase A: gather-sum with TWO-ROW interleave (2 chains x 4 loads in flight).
__global__ __launch_bounds__(256) void k_agg_gemm(
    const int* __restrict__ off_g, const int* __restrict__ elist_g,
    const float* __restrict__ x, float* __restrict__ h_out,
    const short* __restrict__ whiF, const short* __restrict__ wloF,
    const float* __restrict__ bl, const float* __restrict__ pw,
    float* __restrict__ score, int npg)
{
  __shared__ float sA[64 * 128];   // 32 KB, float4-slot XOR swizzle
  __shared__ float cntA[64];
  const int g     = blockIdx.x & 63;
  const int slice = blockIdx.x >> 6;
  const int nodeBase = g * npg;
  const int vbase = slice * 64;
  const int t = threadIdx.x;
  float4* sA4 = (float4*)sA;

  // ---- phase A ----
  {
    const int gr = t >> 5, l32 = t & 31;
    const int* off = off_g + g * 1025;
    const int* el  = elist_g + g * EPG;
    #pragma unroll
    for (int ip = 0; ip < 4; ++ip) {
      const int vbA = gr * 8 + ip * 2, vbB = vbA + 1;
      const int vA = vbase + vbA, vB = vbase + vbB;
      float4 accA = {0.f,0.f,0.f,0.f}, accB = {0.f,0.f,0.f,0.f};
      int eA = 0, endA = 0, eB = 0, endB = 0;
      if (vA < npg) { eA = off[vA]; endA = off[vA + 1]; }
      if (vB < npg) { eB = off[vB]; endB = off[vB + 1]; }
      const int cnA = endA - eA, cnB = endB - eB;
      // paired main loop: 8 independent loads in flight
      while (eA + 4 <= endA && eB + 4 <= endB) {
        int a0 = el[eA], a1 = el[eA+1], a2 = el[eA+2], a3 = el[eA+3];
        int b0 = el[eB], b1 = el[eB+1], b2 = el[eB+2], b3 = el[eB+3];
        float4 xa0 = ((const float4*)(x + (size_t)a0 * DIM))[l32];
        float4 xa1 = ((const float4*)(x + (size_t)a1 * DIM))[l32];
        float4 xa2 = ((const float4*)(x + (size_t)a2 * DIM))[l32];
        float4 xa3 = ((const float4*)(x + (size_t)a3 * DIM))[l32];
        float4 xb0 = ((const float4*)(x + (size_t)b0 * DIM))[l32];
        float4 xb1 = ((const float4*)(x + (size_t)b1 * DIM))[l32];
        float4 xb2 = ((const float4*)(x + (size_t)b2 * DIM))[l32];
        float4 xb3 = ((const float4*)(x + (size_t)b3 * DIM))[l32];
        accA.x += (xa0.x + xa1.x) + (xa2.x + xa3.x);
        accA.y += (xa0.y + xa1.y) + (xa2.y + xa3.y);
        accA.z += (xa0.z + xa1.z) + (xa2.z + xa3.z);
        accA.w += (xa0.w + xa1.w) + (xa2.w + xa3.w);
        accB.x += (xb0.x + xb1.x) + (xb2.x + xb3.x);
        accB.y += (xb0.y + xb1.y) + (xb2.y + xb3.y);
        accB.z += (xb0.z + xb1.z) + (xb2.z + xb3.z);
        accB.w += (xb0.w + xb1.w) + (xb2.w + xb3.w);
        eA += 4; eB += 4;
      }
      drain_row(el, x, l32, eA, endA, accA);
      drain_row(el, x, l32, eB, endB, accB);
      sA4[vbA * 32 + (l32 ^ (vbA & 7))] = accA;
      sA4[vbB * 32 + (l32 ^ (vbB & 7))] = accB;
      if (l32 == 0) { cntA[vbA] = (float)cnA; cntA[vbB] = (float)cnB; }
    }
  }
  __syncthreads();

  // ---- phase B: MFMA GEMM ----
  const int wv = t >> 6, l = t & 63;
  const int lrow = l & 15, lk = l >> 4;      // lk 0..3
  const int rb = wv * 16;
  const int rowb = rb + lrow;
  const int rsw = rowb & 7;
  const int rowg = nodeBase + min(vbase + rowb, npg - 1);
  const float invc = 1.0f / fmaxf(cntA[rowb], 1.0f);
  f32x4 acc[8];
  #pragma unroll
  for (int nt = 0; nt < 8; ++nt) acc[nt] = (f32x4){0.f, 0.f, 0.f, 0.f};
  const float4* sArow = sA4 + rowb * 32;
  const float* xrow = x + (size_t)rowg * DIM + lk * 8;
  const short8v* bh = (const short8v*)whiF;
  const short8v* bo = (const short8v*)wloF;

  #pragma unroll
  for (int kk = 0; kk < 8; ++kk) {
    float av[8];
    if (kk < 4) {
      int sbase = kk * 8 + lk * 2;
      float4 a0 = sArow[(sbase + 0) ^ rsw];
      float4 a1 = sArow[(sbase + 1) ^ rsw];
      av[0] = a0.x * invc; av[1] = a0.y * invc;
      av[2] = a0.z * invc; av[3] = a0.w * invc;
      av[4] = a1.x * invc; av[5] = a1.y * invc;
      av[6] = a1.z * invc; av[7] = a1.w * invc;
    } else {
      float4 a0 = *(const float4*)(xrow + (kk - 4) * 32);
      float4 a1 = *(const float4*)(xrow + (kk - 4) * 32 + 4);
      av[0] = a0.x; av[1] = a0.y; av[2] = a0.z; av[3] = a0.w;
      av[4] = a1.x; av[5] = a1.y; av[6] = a1.z; av[7] = a1.w;
    }
    short8v ahi, alo;
    #pragma unroll
    for (int j = 0; j < 8; ++j) {
      unsigned hb = bf16rne(av[j]);
      float hif = __uint_as_float(hb << 16);
      ahi[j] = (short)hb;
      alo[j] = (short)bf16rne(av[j] - hif);
    }
    #pragma unroll
    for (int nt = 0; nt < 8; ++nt) {
      int fi = (kk * 8 + nt) * 64 + l;
      short8v bhi = bh[fi];
      short8v blo = bo[fi];
      acc[nt] = __builtin_amdgcn_mfma_f32_16x16x32_bf16(ahi, bhi, acc[nt], 0, 0, 0);
      acc[nt] = __builtin_amdgcn_mfma_f32_16x16x32_bf16(alo, bhi, acc[nt], 0, 0, 0);
      acc[nt] = __builtin_amdgcn_mfma_f32_16x16x32_bf16(ahi, blo, acc[nt], 0, 0, 0);
    }
  }

  float sp0 = 0.f, sp1 = 0.f, sp2 = 0.f, sp3 = 0.f;
  const int mbv = vbase + rb + lk * 4;
  #pragma unroll
  for (int nt = 0; nt < 8; ++nt) {
    int col = nt * 16 + lrow;
    float bb = bl[col], pv = pw[col];
    float h0 = fmaxf(acc[nt][0] + bb, 0.f);
    float h1 = fmaxf(acc[nt][1] + bb, 0.f);
    float h2 = fmaxf(acc[nt][2] + bb, 0.f);
    float h3 = fmaxf(acc[nt][3] + bb, 0.f);
    if (mbv + 0 < npg) h_out[(size_t)(nodeBase + mbv + 0) * DIM + col] = h0;
    if (mbv + 1 < npg) h_out[(size_t)(nodeBase + mbv + 1) * DIM + col] = h1;
    if (mbv + 2 < npg) h_out[(size_t)(nodeBase + mbv + 2) * DIM + col] = h2;
    if (mbv + 3 < npg) h_out[(size_t)(nodeBase + mbv + 3) * DIM + col] = h3;
    sp0 += h0 * pv; sp1 += h1 * pv; sp2 += h2 * pv; sp3 += h3 * pv;
  }
  #pragma unroll
  for (int off = 1; off <= 8; off <<= 1) {
    sp0 += __shfl_xor(sp0, off);
    sp1 += __shfl_xor(sp1, off);
    sp2 += __shfl_xor(sp2, off);
    sp3 += __shfl_xor(sp3, off);
  }
  if (lrow == 0) {
    if (mbv + 0 < npg) score[nodeBase + mbv + 0] = sp0;
    if (mbv + 1 < npg) score[nodeBase + mbv + 1] = sp1;
    if (mbv + 2 < npg) score[nodeBase + mbv + 2] = sp2;
    if (mbv + 3 < npg) score[nodeBase + mbv + 3] = sp3;
  }
}

// ------- fused: shuffle-bitonic top-k + relabel + build next CSR ----------
// (key,idx) live in registers; strides<=32 via __shfl_xor (no barrier),
// strides>=64 via LDS (2 barriers each, 10 steps).
__global__ __launch_bounds__(1024) void k_topk_fused(
    const float* __restrict__ score, const float* __restrict__ inv_norm_p,
    int npg, int k, int* __restrict__ sel_pos, float* __restrict__ sel_scale,
    int build_next, int write_eout,
    const int* __restrict__ ein_src, const int* __restrict__ ein_dst,
    int* __restrict__ eout_src, int* __restrict__ eout_dst,
    int* __restrict__ off_g, int* __restrict__ elist_g, float* __restrict__ c_out)
{
  __shared__ float key[1024];
  __shared__ int   idxs[1024];
  __shared__ int   nid[1024];
  __shared__ int   cnt[1024];
  __shared__ int   cur[1024];
  __shared__ int   wsum[16];
  const int t = threadIdx.x, g = blockIdx.x;
  const int base = g * npg;
  float rk = (t < npg) ? score[base + t] : -3.402823466e38f;
  int   ri = t;
  nid[t] = -1;
  cnt[t] = 0;

  #pragma unroll
  for (int size = 2; size <= 1024; size <<= 1) {
    // LDS steps: stride >= 64
    for (int stride = size >> 1; stride >= 64; stride >>= 1) {
      key[t] = rk; idxs[t] = ri;
      __syncthreads();
      float km = key[t ^ stride];
      int   im = idxs[t ^ stride];
      __syncthreads();
      bool mf = (rk > km) || (rk == km && ri < im);
      bool desc = ((t & size) == 0);
      bool lower = ((t & stride) == 0);
      bool keep = desc ? (lower ? mf : !mf) : (lower ? !mf : mf);
      if (!keep) { rk = km; ri = im; }
    }
    // shuffle steps: stride <= 32
    for (int stride = (size >> 1) > 32 ? 32 : (size >> 1); stride >= 1; stride >>= 1) {
      float km = __shfl_xor(rk, stride);
      int   im = __shfl_xor(ri, stride);
      bool mf = (rk > km) || (rk == km && ri < im);
      bool desc = ((t & size) == 0);
      bool lower = ((t & stride) == 0);
      bool keep = desc ? (lower ? mf : !mf) : (lower ? !mf : mf);
      if (!keep) { rk = km; ri = im; }
    }
  }

  if (t < k) {
    float inv = *inv_norm_p;
    nid[ri] = t;
    sel_pos[g * k + t] = base + ri;
    sel_scale[g * k + t] = tanhf(rk * inv);
  }
  if (!build_next) return;
  __syncthreads();
  const int e0 = g * EPG;
  const int newBase = g * k;
  int lns[8], lnd[8];
  #pragma unroll
  for (int i = 0; i < 8; ++i) {
    int e = e0 + t + i * 1024;
    int sv = ein_src[e];
    int ns = -1, nd = -1;
    if (sv >= 0) {
      int dv = ein_dst[e];
      ns = nid[sv - base];
      nd = nid[dv - base];
      if (ns < 0 || nd < 0) ns = -1;
    }
    lns[i] = ns; lnd[i] = nd;
    if (write_eout) {
      eout_src[e] = (ns >= 0) ? (newBase + ns) : -1;
      eout_dst[e] = (ns >= 0) ? (newBase + nd) : -1;
    }
    if (ns >= 0) atomicAdd(&cnt[nd], 1);
  }
  __syncthreads();
  const int lane = t & 63, w = t >> 6;
  int cv = cnt[t];
  int x = cv;
  #pragma unroll
  for (int off = 1; off < 64; off <<= 1) {
    int y = __shfl_up(x, off);
    if (lane >= off) x += y;
  }
  if (lane == 63) wsum[w] = x;
  __syncthreads();
  if (t < 16) {
    int v = wsum[t];
    #pragma unroll
    for (int off2 = 1; off2 < 16; off2 <<= 1) {
      int y = __shfl_up(v, off2);
      if (t >= off2) v += y;
    }
    wsum[t] = v;
  }
  __syncthreads();
  int incl = x + (w ? wsum[w - 1] : 0);
  int excl = incl - cv;
  cur[t] = excl;
  off_g[g * 1025 + t] = excl;
  if (t < k) c_out[newBase + t] = (float)cv;
  __syncthreads();
  int* elp = elist_g + g * EPG;
  #pragma unroll
  for (int i = 0; i < 8; ++i) {
    if (lns[i] >= 0) {
      int pos = atomicAdd(&cur[lnd[i]], 1);
      elp[pos] = newBase + lns[i];
    }
  }
}

// ------- fused pool + readout partial (float4 rows): block=(graph,chunk) --
__global__ __launch_bounds__(256) void k_pool_part(const float* __restrict__ h,
    const int* __restrict__ sel_pos, const float* __restrict__ sel_scale, int k,
    float* __restrict__ xo, float* __restrict__ pmax, float* __restrict__ psum)
{
  __shared__ float4 smx[256], ssm[256];
  const int b  = blockIdx.x >> 4;
  const int ch = blockIdx.x & (RCHUNK - 1);
  const int rpc = (k + RCHUNK - 1) / RCHUNK;
  const int r0 = ch * rpc;
  const int r1 = min(k, r0 + rpc);
  const int d4  = threadIdx.x & 31;
  const int sub = threadIdx.x >> 5;
  const float NEG = -3.402823466e38f;
  float4 mx = {NEG, NEG, NEG, NEG};
  float4 sm = {0.f, 0.f, 0.f, 0.f};
  for (int r = r0 + sub; r < r1; r += 8) {
    int j = b * k + r;
    float scv = sel_scale[j];
    float4 v = ((const float4*)(h + (size_t)sel_pos[j] * DIM))[d4];
    v.x *= scv; v.y *= scv; v.z *= scv; v.w *= scv;
    ((float4*)(xo + (size_t)j * DIM))[d4] = v;
    mx.x = fmaxf(mx.x, v.x); mx.y = fmaxf(mx.y, v.y);
    mx.z = fmaxf(mx.z, v.z); mx.w = fmaxf(mx.w, v.w);
    sm.x += v.x; sm.y += v.y; sm.z += v.z; sm.w += v.w;
  }
  smx[threadIdx.x] = mx; ssm[threadIdx.x] = sm;
  __syncthreads();
  if (sub < 4) {
    #pragma unroll
    for (int step = 4; step >= 1; step >>= 1) {
      if (sub < step) {
        float4 m2 = smx[(sub + step) * 32 + d4];
        float4 s2 = ssm[(sub + step) * 32 + d4];
        mx = smx[sub * 32 + d4]; sm = ssm[sub * 32 + d4];
        mx.x = fmaxf(mx.x, m2.x); mx.y = fmaxf(mx.y, m2.y);
        mx.z = fmaxf(mx.z, m2.z); mx.w = fmaxf(mx.w, m2.w);
        sm.x += s2.x; sm.y += s2.y; sm.z += s2.z; sm.w += s2.w;
        smx[sub * 32 + d4] = mx; ssm[sub * 32 + d4] = sm;
      }
      __syncthreads();
    }
  }
  if (sub == 0) {
    int o = (b * RCHUNK + ch) * 32 + d4;
    ((float4*)pmax)[o] = smx[d4];
    ((float4*)psum)[o] = ssm[d4];
  }
}

// ------- merged readout: combine all 3 stages' partials into rdT ----------
__global__ __launch_bounds__(128) void k_readout_final3(
    const float* __restrict__ pmax, const float* __restrict__ psum,
    int k0, int k1, int k2, float* __restrict__ rdT)
{
  int b = blockIdx.x, d = threadIdx.x;
  const int ks[3] = {k0, k1, k2};
  float tmx = 0.f, tmn = 0.f;
  #pragma unroll
  for (int s = 0; s < 3; ++s) {
    const float* pm = pmax + (size_t)s * PSTRIDE;
    const float* ps = psum + (size_t)s * PSTRIDE;
    float mx = -3.402823466e38f, sm = 0.f;
    #pragma unroll
    for (int c = 0; c < RCHUNK; ++c) {
      int o = (b * RCHUNK + c) * 128 + d;
      mx = fmaxf(mx, pm[o]);
      sm += ps[o];
    }
    tmx += mx;
    tmn += sm / (float)ks[s];
  }
  rdT[d * 64 + b] = tmx;
  rdT[(128 + d) * 64 + b] = tmn;
}

// ------- MLP fc1 + BN1 + relu: 16 blocks, lane=graph, wave=feature --------
__global__ __launch_bounds__(512) void k_mlp_fc1(const float* __restrict__ rdT,
    const float* __restrict__ fc1_w, const float* __restrict__ fc1_b,
    const float* __restrict__ g1, const float* __restrict__ be1,
    float* __restrict__ y1n)
{
  __shared__ float W[8 * 256];
  __shared__ float R[256 * 64];
  const int t = threadIdx.x, b = blockIdx.x;
  ((float4*)W)[t] = ((const float4*)(fc1_w + (size_t)b * 8 * 256))[t];
  #pragma unroll
  for (int i = 0; i < 8; ++i)
    ((float4*)R)[t + i * 512] = ((const float4*)rdT)[t + i * 512];
  __syncthreads();
  const int g = t & 63, w = t >> 6;
  const float* wrow = W + w * 256;
  float acc = 0.f;
  #pragma unroll 4
  for (int k = 0; k < 256; ++k) acc += R[k * 64 + g] * wrow[k];
  int f = b * 8 + w;
  float y = acc + fc1_b[f];
  float s = y, s2 = y * y;
  #pragma unroll
  for (int off = 32; off; off >>= 1) {
    s  += __shfl_xor(s,  off);
    s2 += __shfl_xor(s2, off);
  }
  float mu = s * 0.015625f;
  float var = s2 * 0.015625f - mu * mu;
  float inv = 1.0f / sqrtf(var + 1e-5f);
  y1n[f * 64 + g] = fmaxf((y - mu) * inv * g1[f] + be1[f], 0.f);
}

// ------- MLP rest: fc2 + BN2 + relu + lin + sigmoid (1 block) -------------
__global__ __launch_bounds__(1024) void k_mlp_rest(const float* __restrict__ y1n,
    const float* __restrict__ fc2_w, const float* __restrict__ fc2_b,
    const float* __restrict__ g2, const float* __restrict__ be2,
    const float* __restrict__ lin_w, const float* __restrict__ lin_b,
    float* __restrict__ out)
{
  __shared__ float W2[64 * 128];
  __shared__ float Y[128 * 64];
  __shared__ float part[16 * 64];
  const int t = threadIdx.x;
  #pragma unroll
  for (int i = 0; i < 2; ++i) {
    ((float4*)W2)[t + i * 1024] = ((const float4*)fc2_w)[t + i * 1024];
    ((float4*)Y) [t + i * 1024] = ((const float4*)y1n)[t + i * 1024];
  }
  __syncthreads();
  const int g = t & 63, w = t >> 6;
  float acc2[4] = {0.f, 0.f, 0.f, 0.f};
  const float* w20 = W2 + (w * 4 + 0) * 128;
  const float* w21 = W2 + (w * 4 + 1) * 128;
  const float* w22 = W2 + (w * 4 + 2) * 128;
  const float* w23 = W2 + (w * 4 + 3) * 128;
  #pragma unroll 4
  for (int k = 0; k < 128; ++k) {
    float yv = Y[k * 64 + g];
    acc2[0] += yv * w20[k];
    acc2[1] += yv * w21[k];
    acc2[2] += yv * w22[k];
    acc2[3] += yv * w23[k];
  }
  float pp = 0.f;
  #pragma unroll
  for (int j = 0; j < 4; ++j) {
    int m = w * 4 + j;
    float y = acc2[j] + fc2_b[m];
    float s = y, s2 = y * y;
    #pragma unroll
    for (int off = 32; off; off >>= 1) {
      s  += __shfl_xor(s,  off);
      s2 += __shfl_xor(s2, off);
    }
    float mu = s * 0.015625f;
    float var = s2 * 0.015625f - mu * mu;
    float inv = 1.0f / sqrtf(var + 1e-5f);
    float yn = fmaxf((y - mu) * inv * g2[m] + be2[m], 0.f);
    pp += yn * lin_w[m];
  }
  part[w * 64 + g] = pp;
  __syncthreads();
  if (w == 0) {
    float a = lin_b[0];
    #pragma unroll
    for (int c = 0; c < 16; ++c) a += part[c * 64 + g];
    out[g] = 1.0f / (1.0f + expf(-a));
  }
}

extern "C" void kernel_launch(void* const* d_in, const int* in_sizes, int n_in,
                              void* d_out, int out_size, void* d_ws, size_t ws_size,
                              hipStream_t stream) {
  const int*   node_idx = (const int*)  d_in[0];
  const int*   edge_idx = (const int*)  d_in[1];
  const float* emb      = (const float*)d_in[2];
  const float* w1l      = (const float*)d_in[3];
  const float* b1l      = (const float*)d_in[4];
  const float* w1r      = (const float*)d_in[5];
  const float* pool_w   = (const float*)d_in[6];
  const float* w2l      = (const float*)d_in[7];
  const float* b2l      = (const float*)d_in[8];
  const float* w2r      = (const float*)d_in[9];
  const float* fc1_w    = (const float*)d_in[10];
  const float* fc1_b    = (const float*)d_in[11];
  const float* bn1_g    = (const float*)d_in[12];
  const float* bn1_b    = (const float*)d_in[13];
  const float* fc2_w    = (const float*)d_in[14];
  const float* fc2_b    = (const float*)d_in[15];
  const float* bn2_g    = (const float*)d_in[16];
  const float* bn2_b    = (const float*)d_in[17];
  const float* lin_w    = (const float*)d_in[18];
  const float* lin_b    = (const float*)d_in[19];
  float* out = (float*)d_out;

  char* p = (char*)d_ws;
  auto alloc = [&](size_t bytes) -> void* {
    void* r = (void*)p;
    p += (bytes + 255) & ~(size_t)255;
    return r;
  };
  float* x_cur     = (float*)alloc((size_t)NNODE * DIM * 4);
  float* s_buf     = (float*)alloc((size_t)NNODE * DIM * 4);
  float* c_buf     = (float*)alloc((size_t)NNODE * 4);
  float* score     = (float*)alloc((size_t)NNODE * 4);
  int*   sel_pos   = (int*)  alloc((size_t)NGRAPH * 820 * 4);
  float* sel_scale = (float*)alloc((size_t)NGRAPH * 820 * 4);
  int*   src_cur   = (int*)  alloc((size_t)NEDGE * 4);
  int*   dst_cur   = (int*)  alloc((size_t)NEDGE * 4);
  int*   off_g     = (int*)  alloc((size_t)NGRAPH * 1025 * 4);
  int*   elist_g   = (int*)  alloc((size_t)NGRAPH * EPG * 4);
  float* rdT       = (float*)alloc((size_t)256 * 64 * 4);
  short* whiF      = (short*)alloc((size_t)2 * 32768 * 2);
  short* wloF      = (short*)alloc((size_t)2 * 32768 * 2);
  float* y1n       = (float*)alloc((size_t)128 * 64 * 4);
  float* pmax      = (float*)alloc(PSTRIDE * 3 * 4);
  float* psum      = (float*)alloc(PSTRIDE * 3 * 4);
  float* inv_norm  = (float*)alloc(256);

  k_gather<<<NNODE * 32 / 256, 256, 0, stream>>>(emb, node_idx, x_cur);
  k_norm<<<1, 64, 0, stream>>>(pool_w, inv_norm);
  k_prep_wfrag<<<256, 256, 0, stream>>>(w1l, w1r, w2l, w2r, whiF, wloF);
  k_csr0<<<NGRAPH, 1024, 0, stream>>>(edge_idx, off_g, elist_g, c_buf);

  const int Ks[3] = {820, 656, 525};
  int npg = NPG0;
  for (int stage = 0; stage < 3; ++stage) {
    const short* whi_s = whiF + (stage ? 32768 : 0);
    const short* wlo_s = wloF + (stage ? 32768 : 0);
    const float* bl    = stage ? b2l : b1l;
    int k = Ks[stage];
    int slices = (npg + 63) >> 6;

    k_agg_gemm<<<slices * 64, 256, 0, stream>>>(off_g, elist_g, x_cur, s_buf,
                                                whi_s, wlo_s, bl, pool_w,
                                                score, npg);
    const int* ein_s = (stage == 0) ? edge_idx          : src_cur;
    const int* ein_d = (stage == 0) ? (edge_idx + NEDGE) : dst_cur;
    k_topk_fused<<<NGRAPH, 1024, 0, stream>>>(score, inv_norm, npg, k,
        sel_pos, sel_scale,
        (stage < 2) ? 1 : 0, (stage == 0) ? 1 : 0,
        ein_s, ein_d, src_cur, dst_cur,
        off_g, elist_g, c_buf);
    k_pool_part<<<NGRAPH * RCHUNK, 256, 0, stream>>>(s_buf, sel_pos, sel_scale, k,
        x_cur, pmax + (size_t)stage * PSTRIDE, psum + (size_t)stage * PSTRIDE);
    npg = k;
  }

  k_readout_final3<<<NGRAPH, 128, 0, stream>>>(pmax, psum, Ks[0], Ks[1], Ks[2], rdT);
  k_mlp_fc1<<<16, 512, 0, stream>>>(rdT, fc1_w, fc1_b, bn1_g, bn1_b, y1n);
  k_mlp_rest<<<1, 1024, 0, stream>>>(y1n, fc2_w, fc2_b, bn2_g, bn2_b,
                                     lin_w, lin_b, out);
}

// Round 14
// 264.588 us; speedup vs baseline: 1.3081x; 1.0033x over previous
//
#include <hip/hip_runtime.h>
#include <hip/hip_bf16.h>
#include <cstdint>
#include <cstddef>

#define NGRAPH 64
#define NPG0   1024
#define NNODE  65536     // NGRAPH*NPG0
#define NEDGE  524288
#define EPG    8192      // NEDGE/NGRAPH
#define DIM    128
#define RCHUNK 16        // readout partial chunks per graph
#define PSTRIDE ((size_t)NGRAPH * RCHUNK * 128)
#define AROWS  32        // rows per k_agg_gemm block

typedef __attribute__((ext_vector_type(8))) short short8v;   // 8 bf16
typedef __attribute__((ext_vector_type(4))) float f32x4;

__device__ __forceinline__ unsigned bf16rne(float f) {
  unsigned u = __float_as_uint(f);
  return (u + 0x7FFFu + ((u >> 16) & 1u)) >> 16;
}

// drain remaining edges of one row (4-batch then singles)
__device__ __forceinline__ void drain_row(const int* __restrict__ el,
    const float* __restrict__ x, int l32, int e, int end, float4& acc)
{
  for (; e + 4 <= end; e += 4) {
    int s0 = el[e], s1 = el[e+1], s2 = el[e+2], s3 = el[e+3];
    float4 a0 = ((const float4*)(x + (size_t)s0 * DIM))[l32];
    float4 a1 = ((const float4*)(x + (size_t)s1 * DIM))[l32];
    float4 a2 = ((const float4*)(x + (size_t)s2 * DIM))[l32];
    float4 a3 = ((const float4*)(x + (size_t)s3 * DIM))[l32];
    acc.x += (a0.x + a1.x) + (a2.x + a3.x);
    acc.y += (a0.y + a1.y) + (a2.y + a3.y);
    acc.z += (a0.z + a1.z) + (a2.z + a3.z);
    acc.w += (a0.w + a1.w) + (a2.w + a3.w);
  }
  for (; e < end; ++e) {
    float4 a = ((const float4*)(x + (size_t)el[e] * DIM))[l32];
    acc.x += a.x; acc.y += a.y; acc.z += a.z; acc.w += a.w;
  }
}

// ---------------- gather x = emb[node_idx] ----------------
__global__ __launch_bounds__(256) void k_gather(const float* __restrict__ emb,
    const int* __restrict__ nid, float* __restrict__ x)
{
  int tid = blockIdx.x * 256 + threadIdx.x;
  int i = tid >> 5, lane = tid & 31;
  int row = nid[i];
  ((float4*)(x + (size_t)i * DIM))[lane] =
      ((const float4*)(emb + (size_t)row * DIM))[lane];
}

// ---------------- 1/||pool_w|| ----------------
__global__ __launch_bounds__(64) void k_norm(const float* __restrict__ pw,
    float* __restrict__ inv_norm)
{
  int t = threadIdx.x;
  float a = pw[t], b = pw[t + 64];
  float v = a * a + b * b;
  for (int off = 32; off; off >>= 1) v += __shfl_xor(v, off);
  if (t == 0) *inv_norm = 1.0f / sqrtf(v);
}

// ------- pre-swizzle weights into MFMA B-fragment layout, bf16 hi/lo ------
__global__ __launch_bounds__(256) void k_prep_wfrag(
    const float* __restrict__ w1l, const float* __restrict__ w1r,
    const float* __restrict__ w2l, const float* __restrict__ w2r,
    short* __restrict__ whiF, short* __restrict__ wloF)
{
  int id = blockIdx.x * 256 + threadIdx.x;    // 0..65535 (2 sets x 32768)
  int set = id >> 15;
  int r = id & 32767;
  int j  = r & 7;
  int l  = (r >> 3) & 63;
  int nt = (r >> 9) & 7;
  int kk = r >> 12;
  int k = kk * 32 + ((l >> 4) & 3) * 8 + j;
  int n = nt * 16 + (l & 15);
  const float* wl = set ? w2l : w1l;
  const float* wr = set ? w2r : w1r;
  float w = (k < 128) ? wl[n * 128 + k] : wr[n * 128 + (k - 128)];
  unsigned hb = bf16rne(w);
  float hif = __uint_as_float(hb << 16);
  unsigned lb = bf16rne(w - hif);
  whiF[id] = (short)hb;
  wloF[id] = (short)lb;
}

// ---------------- stage-0 CSR build straight from edge_idx ----------------
__global__ __launch_bounds__(1024) void k_csr0(const int* __restrict__ ei,
    int* __restrict__ off_g, int* __restrict__ elist_g, float* __restrict__ c_out)
{
  __shared__ int cnt[1024];
  __shared__ int cur[1024];
  __shared__ int wsum[16];
  const int t = threadIdx.x, g = blockIdx.x;
  const int nodeBase = g * NPG0;
  const int e0 = g * EPG;
  cnt[t] = 0;
  __syncthreads();
  int sv8[8], dl8[8];
  #pragma unroll
  for (int i = 0; i < 8; ++i) {
    int e = e0 + t + i * 1024;
    sv8[i] = ei[e];
    dl8[i] = ei[NEDGE + e] - nodeBase;
    atomicAdd(&cnt[dl8[i]], 1);
  }
  __syncthreads();
  const int lane = t & 63, w = t >> 6;
  int cv = cnt[t];
  int x = cv;
  #pragma unroll
  for (int off = 1; off < 64; off <<= 1) {
    int y = __shfl_up(x, off);
    if (lane >= off) x += y;
  }
  if (lane == 63) wsum[w] = x;
  __syncthreads();
  if (t < 16) {
    int v = wsum[t];
    #pragma unroll
    for (int off2 = 1; off2 < 16; off2 <<= 1) {
      int y = __shfl_up(v, off2);
      if (t >= off2) v += y;
    }
    wsum[t] = v;
  }
  __syncthreads();
  int incl = x + (w ? wsum[w - 1] : 0);
  int excl = incl - cv;
  cur[t] = excl;
  int* offp = off_g + g * 1025;
  offp[t] = excl;
  if (t == 1023) offp[1024] = incl;
  c_out[nodeBase + t] = (float)cv;
  __syncthreads();
  int* elp = elist_g + g * EPG;
  #pragma unroll
  for (int i = 0; i < 8; ++i) {
    int pos = atomicAdd(&cur[dl8[i]], 1);
    elp[pos] = sv8[i];
  }
}

// ------- FUSED aggregate + MFMA SAGE layer (32 rows / 128 threads) --------
// blockIdx = slice*64 + g  (XCD affinity: graph -> blockIdx%64 -> fixed XCD)
__global__ __launch_bounds__(128) void k_agg_gemm(
    const int* __restrict__ off_g, const int* __restrict__ elist_g,
    const float* __restrict__ x, float* __restrict__ h_out,
    const short* __restrict__ whiF, const short* __restrict__ wloF,
    const float* __restrict__ bl, const float* __restrict__ pw,
    float* __restrict__ score, int npg)
{
  __shared__ float sA[AROWS * 128];   // 16 KB, float4-slot XOR swizzle
  __shared__ float cntA[AROWS];
  const int g     = blockIdx.x & 63;
  const int slice = blockIdx.x >> 6;
  const int nodeBase = g * npg;
  const int vbase = slice * AROWS;
  const int t = threadIdx.x;
  float4* sA4 = (float4*)sA;

  // ---- phase A: 4 groups x 32 lanes, 8 rows each (two-row interleave) ----
  {
    const int gr = t >> 5, l32 = t & 31;
    const int* off = off_g + g * 1025;
    const int* el  = elist_g + g * EPG;
    #pragma unroll
    for (int ip = 0; ip < 4; ++ip) {
      const int vbA = gr * 8 + ip * 2, vbB = vbA + 1;
      const int vA = vbase + vbA, vB = vbase + vbB;
      float4 accA = {0.f,0.f,0.f,0.f}, accB = {0.f,0.f,0.f,0.f};
      int eA = 0, endA = 0, eB = 0, endB = 0;
      if (vA < npg) { eA = off[vA]; endA = off[vA + 1]; }
      if (vB < npg) { eB = off[vB]; endB = off[vB + 1]; }
      const int cnA = endA - eA, cnB = endB - eB;
      while (eA + 4 <= endA && eB + 4 <= endB) {
        int a0 = el[eA], a1 = el[eA+1], a2 = el[eA+2], a3 = el[eA+3];
        int b0 = el[eB], b1 = el[eB+1], b2 = el[eB+2], b3 = el[eB+3];
        float4 xa0 = ((const float4*)(x + (size_t)a0 * DIM))[l32];
        float4 xa1 = ((const float4*)(x + (size_t)a1 * DIM))[l32];
        float4 xa2 = ((const float4*)(x + (size_t)a2 * DIM))[l32];
        float4 xa3 = ((const float4*)(x + (size_t)a3 * DIM))[l32];
        float4 xb0 = ((const float4*)(x + (size_t)b0 * DIM))[l32];
        float4 xb1 = ((const float4*)(x + (size_t)b1 * DIM))[l32];
        float4 xb2 = ((const float4*)(x + (size_t)b2 * DIM))[l32];
        float4 xb3 = ((const float4*)(x + (size_t)b3 * DIM))[l32];
        accA.x += (xa0.x + xa1.x) + (xa2.x + xa3.x);
        accA.y += (xa0.y + xa1.y) + (xa2.y + xa3.y);
        accA.z += (xa0.z + xa1.z) + (xa2.z + xa3.z);
        accA.w += (xa0.w + xa1.w) + (xa2.w + xa3.w);
        accB.x += (xb0.x + xb1.x) + (xb2.x + xb3.x);
        accB.y += (xb0.y + xb1.y) + (xb2.y + xb3.y);
        accB.z += (xb0.z + xb1.z) + (xb2.z + xb3.z);
        accB.w += (xb0.w + xb1.w) + (xb2.w + xb3.w);
        eA += 4; eB += 4;
      }
      drain_row(el, x, l32, eA, endA, accA);
      drain_row(el, x, l32, eB, endB, accB);
      sA4[vbA * 32 + (l32 ^ (vbA & 7))] = accA;
      sA4[vbB * 32 + (l32 ^ (vbB & 7))] = accB;
      if (l32 == 0) { cntA[vbA] = (float)cnA; cntA[vbB] = (float)cnB; }
    }
  }
  __syncthreads();

  // ---- phase B: MFMA GEMM (2 waves x 16 rows) ----
  const int wv = t >> 6, l = t & 63;
  const int lrow = l & 15, lk = l >> 4;      // lk 0..3
  const int rb = wv * 16;
  const int rowb = rb + lrow;                // 0..31
  const int rsw = rowb & 7;
  const int rowg = nodeBase + min(vbase + rowb, npg - 1);
  const float invc = 1.0f / fmaxf(cntA[rowb], 1.0f);
  f32x4 acc[8];
  #pragma unroll
  for (int nt = 0; nt < 8; ++nt) acc[nt] = (f32x4){0.f, 0.f, 0.f, 0.f};
  const float4* sArow = sA4 + rowb * 32;
  const float* xrow = x + (size_t)rowg * DIM + lk * 8;
  const short8v* bh = (const short8v*)whiF;
  const short8v* bo = (const short8v*)wloF;

  #pragma unroll
  for (int kk = 0; kk < 8; ++kk) {
    float av[8];
    if (kk < 4) {
      int sbase = kk * 8 + lk * 2;
      float4 a0 = sArow[(sbase + 0) ^ rsw];
      float4 a1 = sArow[(sbase + 1) ^ rsw];
      av[0] = a0.x * invc; av[1] = a0.y * invc;
      av[2] = a0.z * invc; av[3] = a0.w * invc;
      av[4] = a1.x * invc; av[5] = a1.y * invc;
      av[6] = a1.z * invc; av[7] = a1.w * invc;
    } else {
      float4 a0 = *(const float4*)(xrow + (kk - 4) * 32);
      float4 a1 = *(const float4*)(xrow + (kk - 4) * 32 + 4);
      av[0] = a0.x; av[1] = a0.y; av[2] = a0.z; av[3] = a0.w;
      av[4] = a1.x; av[5] = a1.y; av[6] = a1.z; av[7] = a1.w;
    }
    short8v ahi, alo;
    #pragma unroll
    for (int j = 0; j < 8; ++j) {
      unsigned hb = bf16rne(av[j]);
      float hif = __uint_as_float(hb << 16);
      ahi[j] = (short)hb;
      alo[j] = (short)bf16rne(av[j] - hif);
    }
    #pragma unroll
    for (int nt = 0; nt < 8; ++nt) {
      int fi = (kk * 8 + nt) * 64 + l;
      short8v bhi = bh[fi];
      short8v blo = bo[fi];
      acc[nt] = __builtin_amdgcn_mfma_f32_16x16x32_bf16(ahi, bhi, acc[nt], 0, 0, 0);
      acc[nt] = __builtin_amdgcn_mfma_f32_16x16x32_bf16(alo, bhi, acc[nt], 0, 0, 0);
      acc[nt] = __builtin_amdgcn_mfma_f32_16x16x32_bf16(ahi, blo, acc[nt], 0, 0, 0);
    }
  }

  float sp0 = 0.f, sp1 = 0.f, sp2 = 0.f, sp3 = 0.f;
  const int mbv = vbase + rb + lk * 4;
  #pragma unroll
  for (int nt = 0; nt < 8; ++nt) {
    int col = nt * 16 + lrow;
    float bb = bl[col], pv = pw[col];
    float h0 = fmaxf(acc[nt][0] + bb, 0.f);
    float h1 = fmaxf(acc[nt][1] + bb, 0.f);
    float h2 = fmaxf(acc[nt][2] + bb, 0.f);
    float h3 = fmaxf(acc[nt][3] + bb, 0.f);
    if (mbv + 0 < npg) h_out[(size_t)(nodeBase + mbv + 0) * DIM + col] = h0;
    if (mbv + 1 < npg) h_out[(size_t)(nodeBase + mbv + 1) * DIM + col] = h1;
    if (mbv + 2 < npg) h_out[(size_t)(nodeBase + mbv + 2) * DIM + col] = h2;
    if (mbv + 3 < npg) h_out[(size_t)(nodeBase + mbv + 3) * DIM + col] = h3;
    sp0 += h0 * pv; sp1 += h1 * pv; sp2 += h2 * pv; sp3 += h3 * pv;
  }
  #pragma unroll
  for (int off = 1; off <= 8; off <<= 1) {
    sp0 += __shfl_xor(sp0, off);
    sp1 += __shfl_xor(sp1, off);
    sp2 += __shfl_xor(sp2, off);
    sp3 += __shfl_xor(sp3, off);
  }
  if (lrow == 0) {
    if (mbv + 0 < npg) score[nodeBase + mbv + 0] = sp0;
    if (mbv + 1 < npg) score[nodeBase + mbv + 1] = sp1;
    if (mbv + 2 < npg) score[nodeBase + mbv + 2] = sp2;
    if (mbv + 3 < npg) score[nodeBase + mbv + 3] = sp3;
  }
}

// ------- fused: shuffle-bitonic top-k + relabel + build next CSR ----------
__global__ __launch_bounds__(1024) void k_topk_fused(
    const float* __restrict__ score, const float* __restrict__ inv_norm_p,
    int npg, int k, int* __restrict__ sel_pos, float* __restrict__ sel_scale,
    int build_next, int write_eout,
    const int* __restrict__ ein_src, const int* __restrict__ ein_dst,
    int* __restrict__ eout_src, int* __restrict__ eout_dst,
    int* __restrict__ off_g, int* __restrict__ elist_g, float* __restrict__ c_out)
{
  __shared__ float key[1024];
  __shared__ int   idxs[1024];
  __shared__ int   nid[1024];
  __shared__ int   cnt[1024];
  __shared__ int   cur[1024];
  __shared__ int   wsum[16];
  const int t = threadIdx.x, g = blockIdx.x;
  const int base = g * npg;
  float rk = (t < npg) ? score[base + t] : -3.402823466e38f;
  int   ri = t;
  nid[t] = -1;
  cnt[t] = 0;

  #pragma unroll
  for (int size = 2; size <= 1024; size <<= 1) {
    for (int stride = size >> 1; stride >= 64; stride >>= 1) {
      key[t] = rk; idxs[t] = ri;
      __syncthreads();
      float km = key[t ^ stride];
      int   im = idxs[t ^ stride];
      __syncthreads();
      bool mf = (rk > km) || (rk == km && ri < im);
      bool desc = ((t & size) == 0);
      bool lower = ((t & stride) == 0);
      bool keep = desc ? (lower ? mf : !mf) : (lower ? !mf : mf);
      if (!keep) { rk = km; ri = im; }
    }
    for (int stride = (size >> 1) > 32 ? 32 : (size >> 1); stride >= 1; stride >>= 1) {
      float km = __shfl_xor(rk, stride);
      int   im = __shfl_xor(ri, stride);
      bool mf = (rk > km) || (rk == km && ri < im);
      bool desc = ((t & size) == 0);
      bool lower = ((t & stride) == 0);
      bool keep = desc ? (lower ? mf : !mf) : (lower ? !mf : mf);
      if (!keep) { rk = km; ri = im; }
    }
  }

  if (t < k) {
    float inv = *inv_norm_p;
    nid[ri] = t;
    sel_pos[g * k + t] = base + ri;
    sel_scale[g * k + t] = tanhf(rk * inv);
  }
  if (!build_next) return;
  __syncthreads();
  const int e0 = g * EPG;
  const int newBase = g * k;
  int lns[8], lnd[8];
  #pragma unroll
  for (int i = 0; i < 8; ++i) {
    int e = e0 + t + i * 1024;
    int sv = ein_src[e];
    int ns = -1, nd = -1;
    if (sv >= 0) {
      int dv = ein_dst[e];
      ns = nid[sv - base];
      nd = nid[dv - base];
      if (ns < 0 || nd < 0) ns = -1;
    }
    lns[i] = ns; lnd[i] = nd;
    if (write_eout) {
      eout_src[e] = (ns >= 0) ? (newBase + ns) : -1;
      eout_dst[e] = (ns >= 0) ? (newBase + nd) : -1;
    }
    if (ns >= 0) atomicAdd(&cnt[nd], 1);
  }
  __syncthreads();
  const int lane = t & 63, w = t >> 6;
  int cv = cnt[t];
  int x = cv;
  #pragma unroll
  for (int off = 1; off < 64; off <<= 1) {
    int y = __shfl_up(x, off);
    if (lane >= off) x += y;
  }
  if (lane == 63) wsum[w] = x;
  __syncthreads();
  if (t < 16) {
    int v = wsum[t];
    #pragma unroll
    for (int off2 = 1; off2 < 16; off2 <<= 1) {
      int y = __shfl_up(v, off2);
      if (t >= off2) v += y;
    }
    wsum[t] = v;
  }
  __syncthreads();
  int incl = x + (w ? wsum[w - 1] : 0);
  int excl = incl - cv;
  cur[t] = excl;
  off_g[g * 1025 + t] = excl;
  if (t < k) c_out[newBase + t] = (float)cv;
  __syncthreads();
  int* elp = elist_g + g * EPG;
  #pragma unroll
  for (int i = 0; i < 8; ++i) {
    if (lns[i] >= 0) {
      int pos = atomicAdd(&cur[lnd[i]], 1);
      elp[pos] = newBase + lns[i];
    }
  }
}

// ------- fused pool + readout partial (float4 rows): block=(graph,chunk) --
__global__ __launch_bounds__(256) void k_pool_part(const float* __restrict__ h,
    const int* __restrict__ sel_pos, const float* __restrict__ sel_scale, int k,
    float* __restrict__ xo, float* __restrict__ pmax, float* __restrict__ psum)
{
  __shared__ float4 smx[256], ssm[256];
  const int b  = blockIdx.x >> 4;
  const int ch = blockIdx.x & (RCHUNK - 1);
  const int rpc = (k + RCHUNK - 1) / RCHUNK;
  const int r0 = ch * rpc;
  const int r1 = min(k, r0 + rpc);
  const int d4  = threadIdx.x & 31;
  const int sub = threadIdx.x >> 5;
  const float NEG = -3.402823466e38f;
  float4 mx = {NEG, NEG, NEG, NEG};
  float4 sm = {0.f, 0.f, 0.f, 0.f};
  for (int r = r0 + sub; r < r1; r += 8) {
    int j = b * k + r;
    float scv = sel_scale[j];
    float4 v = ((const float4*)(h + (size_t)sel_pos[j] * DIM))[d4];
    v.x *= scv; v.y *= scv; v.z *= scv; v.w *= scv;
    ((float4*)(xo + (size_t)j * DIM))[d4] = v;
    mx.x = fmaxf(mx.x, v.x); mx.y = fmaxf(mx.y, v.y);
    mx.z = fmaxf(mx.z, v.z); mx.w = fmaxf(mx.w, v.w);
    sm.x += v.x; sm.y += v.y; sm.z += v.z; sm.w += v.w;
  }
  smx[threadIdx.x] = mx; ssm[threadIdx.x] = sm;
  __syncthreads();
  if (sub < 4) {
    #pragma unroll
    for (int step = 4; step >= 1; step >>= 1) {
      if (sub < step) {
        float4 m2 = smx[(sub + step) * 32 + d4];
        float4 s2 = ssm[(sub + step) * 32 + d4];
        mx = smx[sub * 32 + d4]; sm = ssm[sub * 32 + d4];
        mx.x = fmaxf(mx.x, m2.x); mx.y = fmaxf(mx.y, m2.y);
        mx.z = fmaxf(mx.z, m2.z); mx.w = fmaxf(mx.w, m2.w);
        sm.x += s2.x; sm.y += s2.y; sm.z += s2.z; sm.w += s2.w;
        smx[sub * 32 + d4] = mx; ssm[sub * 32 + d4] = sm;
      }
      __syncthreads();
    }
  }
  if (sub == 0) {
    int o = (b * RCHUNK + ch) * 32 + d4;
    ((float4*)pmax)[o] = smx[d4];
    ((float4*)psum)[o] = ssm[d4];
  }
}

// ------- merged readout: combine all 3 stages' partials into rdT ----------
__global__ __launch_bounds__(128) void k_readout_final3(
    const float* __restrict__ pmax, const float* __restrict__ psum,
    int k0, int k1, int k2, float* __restrict__ rdT)
{
  int b = blockIdx.x, d = threadIdx.x;
  const int ks[3] = {k0, k1, k2};
  float tmx = 0.f, tmn = 0.f;
  #pragma unroll
  for (int s = 0; s < 3; ++s) {
    const float* pm = pmax + (size_t)s * PSTRIDE;
    const float* ps = psum + (size_t)s * PSTRIDE;
    float mx = -3.402823466e38f, sm = 0.f;
    #pragma unroll
    for (int c = 0; c < RCHUNK; ++c) {
      int o = (b * RCHUNK + c) * 128 + d;
      mx = fmaxf(mx, pm[o]);
      sm += ps[o];
    }
    tmx += mx;
    tmn += sm / (float)ks[s];
  }
  rdT[d * 64 + b] = tmx;
  rdT[(128 + d) * 64 + b] = tmn;
}

// ------- MLP fc1 + BN1 + relu: 16 blocks, lane=graph, wave=feature --------
__global__ __launch_bounds__(512) void k_mlp_fc1(const float* __restrict__ rdT,
    const float* __restrict__ fc1_w, const float* __restrict__ fc1_b,
    const float* __restrict__ g1, const float* __restrict__ be1,
    float* __restrict__ y1n)
{
  __shared__ float W[8 * 256];
  __shared__ float R[256 * 64];
  const int t = threadIdx.x, b = blockIdx.x;
  ((float4*)W)[t] = ((const float4*)(fc1_w + (size_t)b * 8 * 256))[t];
  #pragma unroll
  for (int i = 0; i < 8; ++i)
    ((float4*)R)[t + i * 512] = ((const float4*)rdT)[t + i * 512];
  __syncthreads();
  const int g = t & 63, w = t >> 6;
  const float* wrow = W + w * 256;
  float acc = 0.f;
  #pragma unroll 4
  for (int k = 0; k < 256; ++k) acc += R[k * 64 + g] * wrow[k];
  int f = b * 8 + w;
  float y = acc + fc1_b[f];
  float s = y, s2 = y * y;
  #pragma unroll
  for (int off = 32; off; off >>= 1) {
    s  += __shfl_xor(s,  off);
    s2 += __shfl_xor(s2, off);
  }
  float mu = s * 0.015625f;
  float var = s2 * 0.015625f - mu * mu;
  float inv = 1.0f / sqrtf(var + 1e-5f);
  y1n[f * 64 + g] = fmaxf((y - mu) * inv * g1[f] + be1[f], 0.f);
}

// ------- MLP rest: fc2 + BN2 + relu + lin + sigmoid (1 block) -------------
__global__ __launch_bounds__(1024) void k_mlp_rest(const float* __restrict__ y1n,
    const float* __restrict__ fc2_w, const float* __restrict__ fc2_b,
    const float* __restrict__ g2, const float* __restrict__ be2,
    const float* __restrict__ lin_w, const float* __restrict__ lin_b,
    float* __restrict__ out)
{
  __shared__ float W2[64 * 128];
  __shared__ float Y[128 * 64];
  __shared__ float part[16 * 64];
  const int t = threadIdx.x;
  #pragma unroll
  for (int i = 0; i < 2; ++i) {
    ((float4*)W2)[t + i * 1024] = ((const float4*)fc2_w)[t + i * 1024];
    ((float4*)Y) [t + i * 1024] = ((const float4*)y1n)[t + i * 1024];
  }
  __syncthreads();
  const int g = t & 63, w = t >> 6;
  float acc2[4] = {0.f, 0.f, 0.f, 0.f};
  const float* w20 = W2 + (w * 4 + 0) * 128;
  const float* w21 = W2 + (w * 4 + 1) * 128;
  const float* w22 = W2 + (w * 4 + 2) * 128;
  const float* w23 = W2 + (w * 4 + 3) * 128;
  #pragma unroll 4
  for (int k = 0; k < 128; ++k) {
    float yv = Y[k * 64 + g];
    acc2[0] += yv * w20[k];
    acc2[1] += yv * w21[k];
    acc2[2] += yv * w22[k];
    acc2[3] += yv * w23[k];
  }
  float pp = 0.f;
  #pragma unroll
  for (int j = 0; j < 4; ++j) {
    int m = w * 4 + j;
    float y = acc2[j] + fc2_b[m];
    float s = y, s2 = y * y;
    #pragma unroll
    for (int off = 32; off; off >>= 1) {
      s  += __shfl_xor(s,  off);
      s2 += __shfl_xor(s2, off);
    }
    float mu = s * 0.015625f;
    float var = s2 * 0.015625f - mu * mu;
    float inv = 1.0f / sqrtf(var + 1e-5f);
    float yn = fmaxf((y - mu) * inv * g2[m] + be2[m], 0.f);
    pp += yn * lin_w[m];
  }
  part[w * 64 + g] = pp;
  __syncthreads();
  if (w == 0) {
    float a = lin_b[0];
    #pragma unroll
    for (int c = 0; c < 16; ++c) a += part[c * 64 + g];
    out[g] = 1.0f / (1.0f + expf(-a));
  }
}

extern "C" void kernel_launch(void* const* d_in, const int* in_sizes, int n_in,
                              void* d_out, int out_size, void* d_ws, size_t ws_size,
                              hipStream_t stream) {
  const int*   node_idx = (const int*)  d_in[0];
  const int*   edge_idx = (const int*)  d_in[1];
  const float* emb      = (const float*)d_in[2];
  const float* w1l      = (const float*)d_in[3];
  const float* b1l      = (const float*)d_in[4];
  const float* w1r      = (const float*)d_in[5];
  const float* pool_w   = (const float*)d_in[6];
  const float* w2l      = (const float*)d_in[7];
  const float* b2l      = (const float*)d_in[8];
  const float* w2r      = (const float*)d_in[9];
  const float* fc1_w    = (const float*)d_in[10];
  const float* fc1_b    = (const float*)d_in[11];
  const float* bn1_g    = (const float*)d_in[12];
  const float* bn1_b    = (const float*)d_in[13];
  const float* fc2_w    = (const float*)d_in[14];
  const float* fc2_b    = (const float*)d_in[15];
  const float* bn2_g    = (const float*)d_in[16];
  const float* bn2_b    = (const float*)d_in[17];
  const float* lin_w    = (const float*)d_in[18];
  const float* lin_b    = (const float*)d_in[19];
  float* out = (float*)d_out;

  char* p = (char*)d_ws;
  auto alloc = [&](size_t bytes) -> void* {
    void* r = (void*)p;
    p += (bytes + 255) & ~(size_t)255;
    return r;
  };
  float* x_cur     = (float*)alloc((size_t)NNODE * DIM * 4);
  float* s_buf     = (float*)alloc((size_t)NNODE * DIM * 4);
  float* c_buf     = (float*)alloc((size_t)NNODE * 4);
  float* score     = (float*)alloc((size_t)NNODE * 4);
  int*   sel_pos   = (int*)  alloc((size_t)NGRAPH * 820 * 4);
  float* sel_scale = (float*)alloc((size_t)NGRAPH * 820 * 4);
  int*   src_cur   = (int*)  alloc((size_t)NEDGE * 4);
  int*   dst_cur   = (int*)  alloc((size_t)NEDGE * 4);
  int*   off_g     = (int*)  alloc((size_t)NGRAPH * 1025 * 4);
  int*   elist_g   = (int*)  alloc((size_t)NGRAPH * EPG * 4);
  float* rdT       = (float*)alloc((size_t)256 * 64 * 4);
  short* whiF      = (short*)alloc((size_t)2 * 32768 * 2);
  short* wloF      = (short*)alloc((size_t)2 * 32768 * 2);
  float* y1n       = (float*)alloc((size_t)128 * 64 * 4);
  float* pmax      = (float*)alloc(PSTRIDE * 3 * 4);
  float* psum      = (float*)alloc(PSTRIDE * 3 * 4);
  float* inv_norm  = (float*)alloc(256);

  k_gather<<<NNODE * 32 / 256, 256, 0, stream>>>(emb, node_idx, x_cur);
  k_norm<<<1, 64, 0, stream>>>(pool_w, inv_norm);
  k_prep_wfrag<<<256, 256, 0, stream>>>(w1l, w1r, w2l, w2r, whiF, wloF);
  k_csr0<<<NGRAPH, 1024, 0, stream>>>(edge_idx, off_g, elist_g, c_buf);

  const int Ks[3] = {820, 656, 525};
  int npg = NPG0;
  for (int stage = 0; stage < 3; ++stage) {
    const short* whi_s = whiF + (stage ? 32768 : 0);
    const short* wlo_s = wloF + (stage ? 32768 : 0);
    const float* bl    = stage ? b2l : b1l;
    int k = Ks[stage];
    int slices = (npg + AROWS - 1) / AROWS;

    k_agg_gemm<<<slices * 64, 128, 0, stream>>>(off_g, elist_g, x_cur, s_buf,
                                                whi_s, wlo_s, bl, pool_w,
                                                score, npg);
    const int* ein_s = (stage == 0) ? edge_idx          : src_cur;
    const int* ein_d = (stage == 0) ? (edge_idx + NEDGE) : dst_cur;
    k_topk_fused<<<NGRAPH, 1024, 0, stream>>>(score, inv_norm, npg, k,
        sel_pos, sel_scale,
        (stage < 2) ? 1 : 0, (stage == 0) ? 1 : 0,
        ein_s, ein_d, src_cur, dst_cur,
        off_g, elist_g, c_buf);
    k_pool_part<<<NGRAPH * RCHUNK, 256, 0, stream>>>(s_buf, sel_pos, sel_scale, k,
        x_cur, pmax + (size_t)stage * PSTRIDE, psum + (size_t)stage * PSTRIDE);
    npg = k;
  }

  k_readout_final3<<<NGRAPH, 128, 0, stream>>>(pmax, psum, Ks[0], Ks[1], Ks[2], rdT);
  k_mlp_fc1<<<16, 512, 0, stream>>>(rdT, fc1_w, fc1_b, bn1_g, bn1_b, y1n);
  k_mlp_rest<<<1, 1024, 0, stream>>>(y1n, fc2_w, fc2_b, bn2_g, bn2_b,
                                     lin_w, lin_b, out);
}

// Round 15
// 251.437 us; speedup vs baseline: 1.3766x; 1.0523x over previous
//
#include <hip/hip_runtime.h>
#include <hip/hip_bf16.h>
#include <cstdint>
#include <cstddef>

#define NGRAPH 64
#define NPG0   1024
#define NNODE  65536     // NGRAPH*NPG0
#define NEDGE  524288
#define EPG    8192      // NEDGE/NGRAPH
#define DIM    128
#define RCHUNK 16        // readout partial chunks per graph
#define PSTRIDE ((size_t)NGRAPH * RCHUNK * 128)
#define AROWS  32        // rows per k_agg_gemm block

typedef __attribute__((ext_vector_type(8))) short short8v;   // 8 bf16
typedef __attribute__((ext_vector_type(4))) float f32x4;

__device__ __forceinline__ unsigned bf16rne(float f) {
  unsigned u = __float_as_uint(f);
  return (u + 0x7FFFu + ((u >> 16) & 1u)) >> 16;
}
__device__ __forceinline__ unsigned pack2bf(float a, float b) {
  return bf16rne(a) | (bf16rne(b) << 16);
}
__device__ __forceinline__ float bf_lo(unsigned u) { return __uint_as_float(u << 16); }
__device__ __forceinline__ float bf_hi(unsigned u) { return __uint_as_float(u & 0xffff0000u); }

// drain remaining edges of one row (bf16 rows, uint2 = 4 elems per lane)
__device__ __forceinline__ void drain_row(const int* __restrict__ el,
    const uint2* __restrict__ xb, int l32, int e, int end, float4& acc)
{
  for (; e + 4 <= end; e += 4) {
    int s0 = el[e], s1 = el[e+1], s2 = el[e+2], s3 = el[e+3];
    uint2 a0 = xb[(size_t)s0 * 32 + l32];
    uint2 a1 = xb[(size_t)s1 * 32 + l32];
    uint2 a2 = xb[(size_t)s2 * 32 + l32];
    uint2 a3 = xb[(size_t)s3 * 32 + l32];
    acc.x += (bf_lo(a0.x) + bf_lo(a1.x)) + (bf_lo(a2.x) + bf_lo(a3.x));
    acc.y += (bf_hi(a0.x) + bf_hi(a1.x)) + (bf_hi(a2.x) + bf_hi(a3.x));
    acc.z += (bf_lo(a0.y) + bf_lo(a1.y)) + (bf_lo(a2.y) + bf_lo(a3.y));
    acc.w += (bf_hi(a0.y) + bf_hi(a1.y)) + (bf_hi(a2.y) + bf_hi(a3.y));
  }
  for (; e < end; ++e) {
    uint2 a = xb[(size_t)el[e] * 32 + l32];
    acc.x += bf_lo(a.x); acc.y += bf_hi(a.x);
    acc.z += bf_lo(a.y); acc.w += bf_hi(a.y);
  }
}

// ---------------- gather x_bf = bf16(emb[node_idx]) ----------------
__global__ __launch_bounds__(256) void k_gather(const float* __restrict__ emb,
    const int* __restrict__ nid, unsigned short* __restrict__ xbf)
{
  int tid = blockIdx.x * 256 + threadIdx.x;
  int i = tid >> 5, lane = tid & 31;
  int row = nid[i];
  float4 v = ((const float4*)(emb + (size_t)row * DIM))[lane];
  uint2 u;
  u.x = pack2bf(v.x, v.y);
  u.y = pack2bf(v.z, v.w);
  ((uint2*)xbf)[(size_t)i * 32 + lane] = u;
}

// ---------------- 1/||pool_w|| ----------------
__global__ __launch_bounds__(64) void k_norm(const float* __restrict__ pw,
    float* __restrict__ inv_norm)
{
  int t = threadIdx.x;
  float a = pw[t], b = pw[t + 64];
  float v = a * a + b * b;
  for (int off = 32; off; off >>= 1) v += __shfl_xor(v, off);
  if (t == 0) *inv_norm = 1.0f / sqrtf(v);
}

// ------- pre-swizzle weights into MFMA B-fragment layout, bf16 hi/lo ------
__global__ __launch_bounds__(256) void k_prep_wfrag(
    const float* __restrict__ w1l, const float* __restrict__ w1r,
    const float* __restrict__ w2l, const float* __restrict__ w2r,
    short* __restrict__ whiF, short* __restrict__ wloF)
{
  int id = blockIdx.x * 256 + threadIdx.x;    // 0..65535 (2 sets x 32768)
  int set = id >> 15;
  int r = id & 32767;
  int j  = r & 7;
  int l  = (r >> 3) & 63;
  int nt = (r >> 9) & 7;
  int kk = r >> 12;
  int k = kk * 32 + ((l >> 4) & 3) * 8 + j;
  int n = nt * 16 + (l & 15);
  const float* wl = set ? w2l : w1l;
  const float* wr = set ? w2r : w1r;
  float w = (k < 128) ? wl[n * 128 + k] : wr[n * 128 + (k - 128)];
  unsigned hb = bf16rne(w);
  float hif = __uint_as_float(hb << 16);
  unsigned lb = bf16rne(w - hif);
  whiF[id] = (short)hb;
  wloF[id] = (short)lb;
}

// ---------------- stage-0 CSR build straight from edge_idx ----------------
__global__ __launch_bounds__(1024) void k_csr0(const int* __restrict__ ei,
    int* __restrict__ off_g, int* __restrict__ elist_g, float* __restrict__ c_out)
{
  __shared__ int cnt[1024];
  __shared__ int cur[1024];
  __shared__ int wsum[16];
  const int t = threadIdx.x, g = blockIdx.x;
  const int nodeBase = g * NPG0;
  const int e0 = g * EPG;
  cnt[t] = 0;
  __syncthreads();
  int sv8[8], dl8[8];
  #pragma unroll
  for (int i = 0; i < 8; ++i) {
    int e = e0 + t + i * 1024;
    sv8[i] = ei[e];
    dl8[i] = ei[NEDGE + e] - nodeBase;
    atomicAdd(&cnt[dl8[i]], 1);
  }
  __syncthreads();
  const int lane = t & 63, w = t >> 6;
  int cv = cnt[t];
  int x = cv;
  #pragma unroll
  for (int off = 1; off < 64; off <<= 1) {
    int y = __shfl_up(x, off);
    if (lane >= off) x += y;
  }
  if (lane == 63) wsum[w] = x;
  __syncthreads();
  if (t < 16) {
    int v = wsum[t];
    #pragma unroll
    for (int off2 = 1; off2 < 16; off2 <<= 1) {
      int y = __shfl_up(v, off2);
      if (t >= off2) v += y;
    }
    wsum[t] = v;
  }
  __syncthreads();
  int incl = x + (w ? wsum[w - 1] : 0);
  int excl = incl - cv;
  cur[t] = excl;
  int* offp = off_g + g * 1025;
  offp[t] = excl;
  if (t == 1023) offp[1024] = incl;
  c_out[nodeBase + t] = (float)cv;
  __syncthreads();
  int* elp = elist_g + g * EPG;
  #pragma unroll
  for (int i = 0; i < 8; ++i) {
    int pos = atomicAdd(&cur[dl8[i]], 1);
    elp[pos] = sv8[i];
  }
}

// ------- FUSED aggregate + MFMA SAGE layer (bf16 features) ----------------
// blockIdx = slice*64 + g ; 32 rows / 128 threads.
__global__ __launch_bounds__(128) void k_agg_gemm(
    const int* __restrict__ off_g, const int* __restrict__ elist_g,
    const unsigned short* __restrict__ xbf, unsigned short* __restrict__ hbf,
    const short* __restrict__ whiF, const short* __restrict__ wloF,
    const float* __restrict__ bl, const float* __restrict__ pw,
    float* __restrict__ score, int npg)
{
  __shared__ float sA[AROWS * 128];   // 16 KB f32 aggregate tile, XOR swizzle
  __shared__ float cntA[AROWS];
  const int g     = blockIdx.x & 63;
  const int slice = blockIdx.x >> 6;
  const int nodeBase = g * npg;
  const int vbase = slice * AROWS;
  const int t = threadIdx.x;
  float4* sA4 = (float4*)sA;
  const uint2* xb2 = (const uint2*)xbf;

  // ---- phase A: 4 groups x 32 lanes, 8 rows each (two-row interleave) ----
  {
    const int gr = t >> 5, l32 = t & 31;
    const int* off = off_g + g * 1025;
    const int* el  = elist_g + g * EPG;
    #pragma unroll
    for (int ip = 0; ip < 4; ++ip) {
      const int vbA = gr * 8 + ip * 2, vbB = vbA + 1;
      const int vA = vbase + vbA, vB = vbase + vbB;
      float4 accA = {0.f,0.f,0.f,0.f}, accB = {0.f,0.f,0.f,0.f};
      int eA = 0, endA = 0, eB = 0, endB = 0;
      if (vA < npg) { eA = off[vA]; endA = off[vA + 1]; }
      if (vB < npg) { eB = off[vB]; endB = off[vB + 1]; }
      const int cnA = endA - eA, cnB = endB - eB;
      while (eA + 4 <= endA && eB + 4 <= endB) {
        int a0 = el[eA], a1 = el[eA+1], a2 = el[eA+2], a3 = el[eA+3];
        int b0 = el[eB], b1 = el[eB+1], b2 = el[eB+2], b3 = el[eB+3];
        uint2 xa0 = xb2[(size_t)a0 * 32 + l32];
        uint2 xa1 = xb2[(size_t)a1 * 32 + l32];
        uint2 xa2 = xb2[(size_t)a2 * 32 + l32];
        uint2 xa3 = xb2[(size_t)a3 * 32 + l32];
        uint2 xb0 = xb2[(size_t)b0 * 32 + l32];
        uint2 xb1 = xb2[(size_t)b1 * 32 + l32];
        uint2 xv2 = xb2[(size_t)b2 * 32 + l32];
        uint2 xv3 = xb2[(size_t)b3 * 32 + l32];
        accA.x += (bf_lo(xa0.x) + bf_lo(xa1.x)) + (bf_lo(xa2.x) + bf_lo(xa3.x));
        accA.y += (bf_hi(xa0.x) + bf_hi(xa1.x)) + (bf_hi(xa2.x) + bf_hi(xa3.x));
        accA.z += (bf_lo(xa0.y) + bf_lo(xa1.y)) + (bf_lo(xa2.y) + bf_lo(xa3.y));
        accA.w += (bf_hi(xa0.y) + bf_hi(xa1.y)) + (bf_hi(xa2.y) + bf_hi(xa3.y));
        accB.x += (bf_lo(xb0.x) + bf_lo(xb1.x)) + (bf_lo(xv2.x) + bf_lo(xv3.x));
        accB.y += (bf_hi(xb0.x) + bf_hi(xb1.x)) + (bf_hi(xv2.x) + bf_hi(xv3.x));
        accB.z += (bf_lo(xb0.y) + bf_lo(xb1.y)) + (bf_lo(xv2.y) + bf_lo(xv3.y));
        accB.w += (bf_hi(xb0.y) + bf_hi(xb1.y)) + (bf_hi(xv2.y) + bf_hi(xv3.y));
        eA += 4; eB += 4;
      }
      drain_row(el, xb2, l32, eA, endA, accA);
      drain_row(el, xb2, l32, eB, endB, accB);
      sA4[vbA * 32 + (l32 ^ (vbA & 7))] = accA;
      sA4[vbB * 32 + (l32 ^ (vbB & 7))] = accB;
      if (l32 == 0) { cntA[vbA] = (float)cnA; cntA[vbB] = (float)cnB; }
    }
  }
  __syncthreads();

  // ---- phase B: MFMA GEMM (2 waves x 16 rows) ----
  const int wv = t >> 6, l = t & 63;
  const int lrow = l & 15, lk = l >> 4;      // lk 0..3
  const int rb = wv * 16;
  const int rowb = rb + lrow;                // 0..31
  const int rsw = rowb & 7;
  const int rowg = nodeBase + min(vbase + rowb, npg - 1);
  const float invc = 1.0f / fmaxf(cntA[rowb], 1.0f);
  f32x4 acc[8];
  #pragma unroll
  for (int nt = 0; nt < 8; ++nt) acc[nt] = (f32x4){0.f, 0.f, 0.f, 0.f};
  const float4* sArow = sA4 + rowb * 32;
  const uint4* xrow4 = (const uint4*)xbf + (size_t)rowg * 16;   // 16 uint4/row
  const short8v* bh = (const short8v*)whiF;
  const short8v* bo = (const short8v*)wloF;

  #pragma unroll
  for (int kk = 0; kk < 8; ++kk) {
    short8v ahi, alo;
    bool self16 = (kk >= 4);     // self term is exactly bf16 -> skip alo
    if (!self16) {
      int sbase = kk * 8 + lk * 2;
      float4 a0 = sArow[(sbase + 0) ^ rsw];
      float4 a1 = sArow[(sbase + 1) ^ rsw];
      float av[8] = { a0.x * invc, a0.y * invc, a0.z * invc, a0.w * invc,
                      a1.x * invc, a1.y * invc, a1.z * invc, a1.w * invc };
      #pragma unroll
      for (int j = 0; j < 8; ++j) {
        unsigned hb2 = bf16rne(av[j]);
        float hif = __uint_as_float(hb2 << 16);
        ahi[j] = (short)hb2;
        alo[j] = (short)bf16rne(av[j] - hif);
      }
    } else {
      uint4 u = xrow4[(kk - 4) * 4 + lk];
      ahi[0] = (short)(u.x & 0xffff); ahi[1] = (short)(u.x >> 16);
      ahi[2] = (short)(u.y & 0xffff); ahi[3] = (short)(u.y >> 16);
      ahi[4] = (short)(u.z & 0xffff); ahi[5] = (short)(u.z >> 16);
      ahi[6] = (short)(u.w & 0xffff); ahi[7] = (short)(u.w >> 16);
    }
    #pragma unroll
    for (int nt = 0; nt < 8; ++nt) {
      int fi = (kk * 8 + nt) * 64 + l;
      short8v bhi = bh[fi];
      short8v blo = bo[fi];
      acc[nt] = __builtin_amdgcn_mfma_f32_16x16x32_bf16(ahi, bhi, acc[nt], 0, 0, 0);
      if (!self16)
        acc[nt] = __builtin_amdgcn_mfma_f32_16x16x32_bf16(alo, bhi, acc[nt], 0, 0, 0);
      acc[nt] = __builtin_amdgcn_mfma_f32_16x16x32_bf16(ahi, blo, acc[nt], 0, 0, 0);
    }
  }

  float sp0 = 0.f, sp1 = 0.f, sp2 = 0.f, sp3 = 0.f;
  const int mbv = vbase + rb + lk * 4;
  #pragma unroll
  for (int nt = 0; nt < 8; ++nt) {
    int col = nt * 16 + lrow;
    float bb = bl[col], pv = pw[col];
    float h0 = fmaxf(acc[nt][0] + bb, 0.f);
    float h1 = fmaxf(acc[nt][1] + bb, 0.f);
    float h2 = fmaxf(acc[nt][2] + bb, 0.f);
    float h3 = fmaxf(acc[nt][3] + bb, 0.f);
    if (mbv + 0 < npg) hbf[(size_t)(nodeBase + mbv + 0) * DIM + col] = (unsigned short)bf16rne(h0);
    if (mbv + 1 < npg) hbf[(size_t)(nodeBase + mbv + 1) * DIM + col] = (unsigned short)bf16rne(h1);
    if (mbv + 2 < npg) hbf[(size_t)(nodeBase + mbv + 2) * DIM + col] = (unsigned short)bf16rne(h2);
    if (mbv + 3 < npg) hbf[(size_t)(nodeBase + mbv + 3) * DIM + col] = (unsigned short)bf16rne(h3);
    sp0 += h0 * pv; sp1 += h1 * pv; sp2 += h2 * pv; sp3 += h3 * pv;
  }
  #pragma unroll
  for (int off = 1; off <= 8; off <<= 1) {
    sp0 += __shfl_xor(sp0, off);
    sp1 += __shfl_xor(sp1, off);
    sp2 += __shfl_xor(sp2, off);
    sp3 += __shfl_xor(sp3, off);
  }
  if (lrow == 0) {
    if (mbv + 0 < npg) score[nodeBase + mbv + 0] = sp0;
    if (mbv + 1 < npg) score[nodeBase + mbv + 1] = sp1;
    if (mbv + 2 < npg) score[nodeBase + mbv + 2] = sp2;
    if (mbv + 3 < npg) score[nodeBase + mbv + 3] = sp3;
  }
}

// ------- fused: shuffle-bitonic top-k + relabel + build next CSR ----------
__global__ __launch_bounds__(1024) void k_topk_fused(
    const float* __restrict__ score, const float* __restrict__ inv_norm_p,
    int npg, int k, int* __restrict__ sel_pos, float* __restrict__ sel_scale,
    int build_next, int write_eout,
    const int* __restrict__ ein_src, const int* __restrict__ ein_dst,
    int* __restrict__ eout_src, int* __restrict__ eout_dst,
    int* __restrict__ off_g, int* __restrict__ elist_g, float* __restrict__ c_out)
{
  __shared__ float key[1024];
  __shared__ int   idxs[1024];
  __shared__ int   nid[1024];
  __shared__ int   cnt[1024];
  __shared__ int   cur[1024];
  __shared__ int   wsum[16];
  const int t = threadIdx.x, g = blockIdx.x;
  const int base = g * npg;
  float rk = (t < npg) ? score[base + t] : -3.402823466e38f;
  int   ri = t;
  nid[t] = -1;
  cnt[t] = 0;

  #pragma unroll
  for (int size = 2; size <= 1024; size <<= 1) {
    for (int stride = size >> 1; stride >= 64; stride >>= 1) {
      key[t] = rk; idxs[t] = ri;
      __syncthreads();
      float km = key[t ^ stride];
      int   im = idxs[t ^ stride];
      __syncthreads();
      bool mf = (rk > km) || (rk == km && ri < im);
      bool desc = ((t & size) == 0);
      bool lower = ((t & stride) == 0);
      bool keep = desc ? (lower ? mf : !mf) : (lower ? !mf : mf);
      if (!keep) { rk = km; ri = im; }
    }
    for (int stride = (size >> 1) > 32 ? 32 : (size >> 1); stride >= 1; stride >>= 1) {
      float km = __shfl_xor(rk, stride);
      int   im = __shfl_xor(ri, stride);
      bool mf = (rk > km) || (rk == km && ri < im);
      bool desc = ((t & size) == 0);
      bool lower = ((t & stride) == 0);
      bool keep = desc ? (lower ? mf : !mf) : (lower ? !mf : mf);
      if (!keep) { rk = km; ri = im; }
    }
  }

  if (t < k) {
    float inv = *inv_norm_p;
    nid[ri] = t;
    sel_pos[g * k + t] = base + ri;
    sel_scale[g * k + t] = tanhf(rk * inv);
  }
  if (!build_next) return;
  __syncthreads();
  const int e0 = g * EPG;
  const int newBase = g * k;
  int lns[8], lnd[8];
  #pragma unroll
  for (int i = 0; i < 8; ++i) {
    int e = e0 + t + i * 1024;
    int sv = ein_src[e];
    int ns = -1, nd = -1;
    if (sv >= 0) {
      int dv = ein_dst[e];
      ns = nid[sv - base];
      nd = nid[dv - base];
      if (ns < 0 || nd < 0) ns = -1;
    }
    lns[i] = ns; lnd[i] = nd;
    if (write_eout) {
      eout_src[e] = (ns >= 0) ? (newBase + ns) : -1;
      eout_dst[e] = (ns >= 0) ? (newBase + nd) : -1;
    }
    if (ns >= 0) atomicAdd(&cnt[nd], 1);
  }
  __syncthreads();
  const int lane = t & 63, w = t >> 6;
  int cv = cnt[t];
  int x = cv;
  #pragma unroll
  for (int off = 1; off < 64; off <<= 1) {
    int y = __shfl_up(x, off);
    if (lane >= off) x += y;
  }
  if (lane == 63) wsum[w] = x;
  __syncthreads();
  if (t < 16) {
    int v = wsum[t];
    #pragma unroll
    for (int off2 = 1; off2 < 16; off2 <<= 1) {
      int y = __shfl_up(v, off2);
      if (t >= off2) v += y;
    }
    wsum[t] = v;
  }
  __syncthreads();
  int incl = x + (w ? wsum[w - 1] : 0);
  int excl = incl - cv;
  cur[t] = excl;
  off_g[g * 1025 + t] = excl;
  if (t < k) c_out[newBase + t] = (float)cv;
  __syncthreads();
  int* elp = elist_g + g * EPG;
  #pragma unroll
  for (int i = 0; i < 8; ++i) {
    if (lns[i] >= 0) {
      int pos = atomicAdd(&cur[lnd[i]], 1);
      elp[pos] = newBase + lns[i];
    }
  }
}

// ------- fused pool + readout partial (bf16 rows): block=(graph,chunk) ----
__global__ __launch_bounds__(256) void k_pool_part(const unsigned short* __restrict__ hbf,
    const int* __restrict__ sel_pos, const float* __restrict__ sel_scale, int k,
    unsigned short* __restrict__ xbf, float* __restrict__ pmax, float* __restrict__ psum)
{
  __shared__ float4 smx[256], ssm[256];
  const int b  = blockIdx.x >> 4;
  const int ch = blockIdx.x & (RCHUNK - 1);
  const int rpc = (k + RCHUNK - 1) / RCHUNK;
  const int r0 = ch * rpc;
  const int r1 = min(k, r0 + rpc);
  const int d4  = threadIdx.x & 31;
  const int sub = threadIdx.x >> 5;
  const float NEG = -3.402823466e38f;
  const uint2* hb2 = (const uint2*)hbf;
  uint2* xb2 = (uint2*)xbf;
  float4 mx = {NEG, NEG, NEG, NEG};
  float4 sm = {0.f, 0.f, 0.f, 0.f};
  for (int r = r0 + sub; r < r1; r += 8) {
    int j = b * k + r;
    float scv = sel_scale[j];
    uint2 u = hb2[(size_t)sel_pos[j] * 32 + d4];
    float4 v;
    v.x = bf_lo(u.x) * scv; v.y = bf_hi(u.x) * scv;
    v.z = bf_lo(u.y) * scv; v.w = bf_hi(u.y) * scv;
    uint2 o;
    o.x = pack2bf(v.x, v.y);
    o.y = pack2bf(v.z, v.w);
    xb2[(size_t)j * 32 + d4] = o;
    // readout uses the bf16-rounded stored values for max/mean consistency
    v.x = bf_lo(o.x); v.y = bf_hi(o.x); v.z = bf_lo(o.y); v.w = bf_hi(o.y);
    mx.x = fmaxf(mx.x, v.x); mx.y = fmaxf(mx.y, v.y);
    mx.z = fmaxf(mx.z, v.z); mx.w = fmaxf(mx.w, v.w);
    sm.x += v.x; sm.y += v.y; sm.z += v.z; sm.w += v.w;
  }
  smx[threadIdx.x] = mx; ssm[threadIdx.x] = sm;
  __syncthreads();
  if (sub < 4) {
    #pragma unroll
    for (int step = 4; step >= 1; step >>= 1) {
      if (sub < step) {
        float4 m2 = smx[(sub + step) * 32 + d4];
        float4 s2 = ssm[(sub + step) * 32 + d4];
        mx = smx[sub * 32 + d4]; sm = ssm[sub * 32 + d4];
        mx.x = fmaxf(mx.x, m2.x); mx.y = fmaxf(mx.y, m2.y);
        mx.z = fmaxf(mx.z, m2.z); mx.w = fmaxf(mx.w, m2.w);
        sm.x += s2.x; sm.y += s2.y; sm.z += s2.z; sm.w += s2.w;
        smx[sub * 32 + d4] = mx; ssm[sub * 32 + d4] = sm;
      }
      __syncthreads();
    }
  }
  if (sub == 0) {
    int o = (b * RCHUNK + ch) * 32 + d4;
    ((float4*)pmax)[o] = smx[d4];
    ((float4*)psum)[o] = ssm[d4];
  }
}

// ------- merged readout: combine all 3 stages' partials into rdT ----------
__global__ __launch_bounds__(128) void k_readout_final3(
    const float* __restrict__ pmax, const float* __restrict__ psum,
    int k0, int k1, int k2, float* __restrict__ rdT)
{
  int b = blockIdx.x, d = threadIdx.x;
  const int ks[3] = {k0, k1, k2};
  float tmx = 0.f, tmn = 0.f;
  #pragma unroll
  for (int s = 0; s < 3; ++s) {
    const float* pm = pmax + (size_t)s * PSTRIDE;
    const float* ps = psum + (size_t)s * PSTRIDE;
    float mx = -3.402823466e38f, sm = 0.f;
    #pragma unroll
    for (int c = 0; c < RCHUNK; ++c) {
      int o = (b * RCHUNK + c) * 128 + d;
      mx = fmaxf(mx, pm[o]);
      sm += ps[o];
    }
    tmx += mx;
    tmn += sm / (float)ks[s];
  }
  rdT[d * 64 + b] = tmx;
  rdT[(128 + d) * 64 + b] = tmn;
}

// ------- MLP fc1 + BN1 + relu: 16 blocks, lane=graph, wave=feature --------
__global__ __launch_bounds__(512) void k_mlp_fc1(const float* __restrict__ rdT,
    const float* __restrict__ fc1_w, const float* __restrict__ fc1_b,
    const float* __restrict__ g1, const float* __restrict__ be1,
    float* __restrict__ y1n)
{
  __shared__ float W[8 * 256];
  __shared__ float R[256 * 64];
  const int t = threadIdx.x, b = blockIdx.x;
  ((float4*)W)[t] = ((const float4*)(fc1_w + (size_t)b * 8 * 256))[t];
  #pragma unroll
  for (int i = 0; i < 8; ++i)
    ((float4*)R)[t + i * 512] = ((const float4*)rdT)[t + i * 512];
  __syncthreads();
  const int g = t & 63, w = t >> 6;
  const float* wrow = W + w * 256;
  float acc = 0.f;
  #pragma unroll 4
  for (int k = 0; k < 256; ++k) acc += R[k * 64 + g] * wrow[k];
  int f = b * 8 + w;
  float y = acc + fc1_b[f];
  float s = y, s2 = y * y;
  #pragma unroll
  for (int off = 32; off; off >>= 1) {
    s  += __shfl_xor(s,  off);
    s2 += __shfl_xor(s2, off);
  }
  float mu = s * 0.015625f;
  float var = s2 * 0.015625f - mu * mu;
  float inv = 1.0f / sqrtf(var + 1e-5f);
  y1n[f * 64 + g] = fmaxf((y - mu) * inv * g1[f] + be1[f], 0.f);
}

// ------- MLP rest: fc2 + BN2 + relu + lin + sigmoid (1 block) -------------
__global__ __launch_bounds__(1024) void k_mlp_rest(const float* __restrict__ y1n,
    const float* __restrict__ fc2_w, const float* __restrict__ fc2_b,
    const float* __restrict__ g2, const float* __restrict__ be2,
    const float* __restrict__ lin_w, const float* __restrict__ lin_b,
    float* __restrict__ out)
{
  __shared__ float W2[64 * 128];
  __shared__ float Y[128 * 64];
  __shared__ float part[16 * 64];
  const int t = threadIdx.x;
  #pragma unroll
  for (int i = 0; i < 2; ++i) {
    ((float4*)W2)[t + i * 1024] = ((const float4*)fc2_w)[t + i * 1024];
    ((float4*)Y) [t + i * 1024] = ((const float4*)y1n)[t + i * 1024];
  }
  __syncthreads();
  const int g = t & 63, w = t >> 6;
  float acc2[4] = {0.f, 0.f, 0.f, 0.f};
  const float* w20 = W2 + (w * 4 + 0) * 128;
  const float* w21 = W2 + (w * 4 + 1) * 128;
  const float* w22 = W2 + (w * 4 + 2) * 128;
  const float* w23 = W2 + (w * 4 + 3) * 128;
  #pragma unroll 4
  for (int k = 0; k < 128; ++k) {
    float yv = Y[k * 64 + g];
    acc2[0] += yv * w20[k];
    acc2[1] += yv * w21[k];
    acc2[2] += yv * w22[k];
    acc2[3] += yv * w23[k];
  }
  float pp = 0.f;
  #pragma unroll
  for (int j = 0; j < 4; ++j) {
    int m = w * 4 + j;
    float y = acc2[j] + fc2_b[m];
    float s = y, s2 = y * y;
    #pragma unroll
    for (int off = 32; off; off >>= 1) {
      s  += __shfl_xor(s,  off);
      s2 += __shfl_xor(s2, off);
    }
    float mu = s * 0.015625f;
    float var = s2 * 0.015625f - mu * mu;
    float inv = 1.0f / sqrtf(var + 1e-5f);
    float yn = fmaxf((y - mu) * inv * g2[m] + be2[m], 0.f);
    pp += yn * lin_w[m];
  }
  part[w * 64 + g] = pp;
  __syncthreads();
  if (w == 0) {
    float a = lin_b[0];
    #pragma unroll
    for (int c = 0; c < 16; ++c) a += part[c * 64 + g];
    out[g] = 1.0f / (1.0f + expf(-a));
  }
}

extern "C" void kernel_launch(void* const* d_in, const int* in_sizes, int n_in,
                              void* d_out, int out_size, void* d_ws, size_t ws_size,
                              hipStream_t stream) {
  const int*   node_idx = (const int*)  d_in[0];
  const int*   edge_idx = (const int*)  d_in[1];
  const float* emb      = (const float*)d_in[2];
  const float* w1l      = (const float*)d_in[3];
  const float* b1l      = (const float*)d_in[4];
  const float* w1r      = (const float*)d_in[5];
  const float* pool_w   = (const float*)d_in[6];
  const float* w2l      = (const float*)d_in[7];
  const float* b2l      = (const float*)d_in[8];
  const float* w2r      = (const float*)d_in[9];
  const float* fc1_w    = (const float*)d_in[10];
  const float* fc1_b    = (const float*)d_in[11];
  const float* bn1_g    = (const float*)d_in[12];
  const float* bn1_b    = (const float*)d_in[13];
  const float* fc2_w    = (const float*)d_in[14];
  const float* fc2_b    = (const float*)d_in[15];
  const float* bn2_g    = (const float*)d_in[16];
  const float* bn2_b    = (const float*)d_in[17];
  const float* lin_w    = (const float*)d_in[18];
  const float* lin_b    = (const float*)d_in[19];
  float* out = (float*)d_out;

  char* p = (char*)d_ws;
  auto alloc = [&](size_t bytes) -> void* {
    void* r = (void*)p;
    p += (bytes + 255) & ~(size_t)255;
    return r;
  };
  unsigned short* x_bf = (unsigned short*)alloc((size_t)NNODE * DIM * 2);
  unsigned short* h_bf = (unsigned short*)alloc((size_t)NNODE * DIM * 2);
  float* c_buf     = (float*)alloc((size_t)NNODE * 4);
  float* score     = (float*)alloc((size_t)NNODE * 4);
  int*   sel_pos   = (int*)  alloc((size_t)NGRAPH * 820 * 4);
  float* sel_scale = (float*)alloc((size_t)NGRAPH * 820 * 4);
  int*   src_cur   = (int*)  alloc((size_t)NEDGE * 4);
  int*   dst_cur   = (int*)  alloc((size_t)NEDGE * 4);
  int*   off_g     = (int*)  alloc((size_t)NGRAPH * 1025 * 4);
  int*   elist_g   = (int*)  alloc((size_t)NGRAPH * EPG * 4);
  float* rdT       = (float*)alloc((size_t)256 * 64 * 4);
  short* whiF      = (short*)alloc((size_t)2 * 32768 * 2);
  short* wloF      = (short*)alloc((size_t)2 * 32768 * 2);
  float* y1n       = (float*)alloc((size_t)128 * 64 * 4);
  float* pmax      = (float*)alloc(PSTRIDE * 3 * 4);
  float* psum      = (float*)alloc(PSTRIDE * 3 * 4);
  float* inv_norm  = (float*)alloc(256);

  k_gather<<<NNODE * 32 / 256, 256, 0, stream>>>(emb, node_idx, x_bf);
  k_norm<<<1, 64, 0, stream>>>(pool_w, inv_norm);
  k_prep_wfrag<<<256, 256, 0, stream>>>(w1l, w1r, w2l, w2r, whiF, wloF);
  k_csr0<<<NGRAPH, 1024, 0, stream>>>(edge_idx, off_g, elist_g, c_buf);

  const int Ks[3] = {820, 656, 525};
  int npg = NPG0;
  for (int stage = 0; stage < 3; ++stage) {
    const short* whi_s = whiF + (stage ? 32768 : 0);
    const short* wlo_s = wloF + (stage ? 32768 : 0);
    const float* bl    = stage ? b2l : b1l;
    int k = Ks[stage];
    int slices = (npg + AROWS - 1) / AROWS;

    k_agg_gemm<<<slices * 64, 128, 0, stream>>>(off_g, elist_g, x_bf, h_bf,
                                                whi_s, wlo_s, bl, pool_w,
                                                score, npg);
    const int* ein_s = (stage == 0) ? edge_idx          : src_cur;
    const int* ein_d = (stage == 0) ? (edge_idx + NEDGE) : dst_cur;
    k_topk_fused<<<NGRAPH, 1024, 0, stream>>>(score, inv_norm, npg, k,
        sel_pos, sel_scale,
        (stage < 2) ? 1 : 0, (stage == 0) ? 1 : 0,
        ein_s, ein_d, src_cur, dst_cur,
        off_g, elist_g, c_buf);
    k_pool_part<<<NGRAPH * RCHUNK, 256, 0, stream>>>(h_bf, sel_pos, sel_scale, k,
        x_bf, pmax + (size_t)stage * PSTRIDE, psum + (size_t)stage * PSTRIDE);
    npg = k;
  }

  k_readout_final3<<<NGRAPH, 128, 0, stream>>>(pmax, psum, Ks[0], Ks[1], Ks[2], rdT);
  k_mlp_fc1<<<16, 512, 0, stream>>>(rdT, fc1_w, fc1_b, bn1_g, bn1_b, y1n);
  k_mlp_rest<<<1, 1024, 0, stream>>>(y1n, fc2_w, fc2_b, bn2_g, bn2_b,
                                     lin_w, lin_b, out);
}

// Round 16
// 248.927 us; speedup vs baseline: 1.3904x; 1.0101x over previous
//
#include <hip/hip_runtime.h>
#include <hip/hip_bf16.h>
#include <cstdint>
#include <cstddef>

#define NGRAPH 64
#define NPG0   1024
#define NNODE  65536     // NGRAPH*NPG0
#define NEDGE  524288
#define EPG    8192      // NEDGE/NGRAPH
#define DIM    128
#define RCHUNK 16        // readout partial chunks per graph
#define PSTRIDE ((size_t)NGRAPH * RCHUNK * 128)
#define AROWS  32        // rows per k_agg_gemm block

typedef __attribute__((ext_vector_type(8))) short short8v;   // 8 bf16
typedef __attribute__((ext_vector_type(4))) float f32x4;

__device__ __forceinline__ unsigned bf16rne(float f) {
  unsigned u = __float_as_uint(f);
  return (u + 0x7FFFu + ((u >> 16) & 1u)) >> 16;
}
__device__ __forceinline__ unsigned pack2bf(float a, float b) {
  return bf16rne(a) | (bf16rne(b) << 16);
}
__device__ __forceinline__ float bf_lo(unsigned u) { return __uint_as_float(u << 16); }
__device__ __forceinline__ float bf_hi(unsigned u) { return __uint_as_float(u & 0xffff0000u); }

__device__ __forceinline__ void add8(float* a, uint4 u) {
  a[0] += bf_lo(u.x); a[1] += bf_hi(u.x);
  a[2] += bf_lo(u.y); a[3] += bf_hi(u.y);
  a[4] += bf_lo(u.z); a[5] += bf_hi(u.z);
  a[6] += bf_lo(u.w); a[7] += bf_hi(u.w);
}

// ---------------- gather x_bf = bf16(emb[node_idx]) ----------------
__global__ __launch_bounds__(256) void k_gather(const float* __restrict__ emb,
    const int* __restrict__ nid, unsigned short* __restrict__ xbf)
{
  int tid = blockIdx.x * 256 + threadIdx.x;
  int i = tid >> 5, lane = tid & 31;
  int row = nid[i];
  float4 v = ((const float4*)(emb + (size_t)row * DIM))[lane];
  uint2 u;
  u.x = pack2bf(v.x, v.y);
  u.y = pack2bf(v.z, v.w);
  ((uint2*)xbf)[(size_t)i * 32 + lane] = u;
}

// ---------------- 1/||pool_w|| ----------------
__global__ __launch_bounds__(64) void k_norm(const float* __restrict__ pw,
    float* __restrict__ inv_norm)
{
  int t = threadIdx.x;
  float a = pw[t], b = pw[t + 64];
  float v = a * a + b * b;
  for (int off = 32; off; off >>= 1) v += __shfl_xor(v, off);
  if (t == 0) *inv_norm = 1.0f / sqrtf(v);
}

// ------- pre-swizzle weights into MFMA B-fragment layout, bf16 hi/lo ------
__global__ __launch_bounds__(256) void k_prep_wfrag(
    const float* __restrict__ w1l, const float* __restrict__ w1r,
    const float* __restrict__ w2l, const float* __restrict__ w2r,
    short* __restrict__ whiF, short* __restrict__ wloF)
{
  int id = blockIdx.x * 256 + threadIdx.x;    // 0..65535 (2 sets x 32768)
  int set = id >> 15;
  int r = id & 32767;
  int j  = r & 7;
  int l  = (r >> 3) & 63;
  int nt = (r >> 9) & 7;
  int kk = r >> 12;
  int k = kk * 32 + ((l >> 4) & 3) * 8 + j;
  int n = nt * 16 + (l & 15);
  const float* wl = set ? w2l : w1l;
  const float* wr = set ? w2r : w1r;
  float w = (k < 128) ? wl[n * 128 + k] : wr[n * 128 + (k - 128)];
  unsigned hb = bf16rne(w);
  float hif = __uint_as_float(hb << 16);
  unsigned lb = bf16rne(w - hif);
  whiF[id] = (short)hb;
  wloF[id] = (short)lb;
}

// ---------------- stage-0 CSR build straight from edge_idx ----------------
__global__ __launch_bounds__(1024) void k_csr0(const int* __restrict__ ei,
    int* __restrict__ off_g, int* __restrict__ elist_g, float* __restrict__ c_out)
{
  __shared__ int cnt[1024];
  __shared__ int cur[1024];
  __shared__ int wsum[16];
  const int t = threadIdx.x, g = blockIdx.x;
  const int nodeBase = g * NPG0;
  const int e0 = g * EPG;
  cnt[t] = 0;
  __syncthreads();
  int sv8[8], dl8[8];
  #pragma unroll
  for (int i = 0; i < 8; ++i) {
    int e = e0 + t + i * 1024;
    sv8[i] = ei[e];
    dl8[i] = ei[NEDGE + e] - nodeBase;
    atomicAdd(&cnt[dl8[i]], 1);
  }
  __syncthreads();
  const int lane = t & 63, w = t >> 6;
  int cv = cnt[t];
  int x = cv;
  #pragma unroll
  for (int off = 1; off < 64; off <<= 1) {
    int y = __shfl_up(x, off);
    if (lane >= off) x += y;
  }
  if (lane == 63) wsum[w] = x;
  __syncthreads();
  if (t < 16) {
    int v = wsum[t];
    #pragma unroll
    for (int off2 = 1; off2 < 16; off2 <<= 1) {
      int y = __shfl_up(v, off2);
      if (t >= off2) v += y;
    }
    wsum[t] = v;
  }
  __syncthreads();
  int incl = x + (w ? wsum[w - 1] : 0);
  int excl = incl - cv;
  cur[t] = excl;
  int* offp = off_g + g * 1025;
  offp[t] = excl;
  if (t == 1023) offp[1024] = incl;
  c_out[nodeBase + t] = (float)cv;
  __syncthreads();
  int* elp = elist_g + g * EPG;
  #pragma unroll
  for (int i = 0; i < 8; ++i) {
    int pos = atomicAdd(&cur[dl8[i]], 1);
    elp[pos] = sv8[i];
  }
}

// ------- FUSED aggregate + MFMA SAGE layer (bf16, 2 rows per load) --------
// blockIdx = slice*64 + g ; 32 rows / 128 threads.
// Phase A: one uint4x32-lane load fetches TWO 256B bf16 rows (lanes 0-15 =
// even edge, 16-31 = odd edge); halves merged by shfl_xor(16) at the end.
__global__ __launch_bounds__(128) void k_agg_gemm(
    const int* __restrict__ off_g, const int* __restrict__ elist_g,
    const unsigned short* __restrict__ xbf, unsigned short* __restrict__ hbf,
    const short* __restrict__ whiF, const short* __restrict__ wloF,
    const float* __restrict__ bl, const float* __restrict__ pw,
    float* __restrict__ score, int npg)
{
  __shared__ float sA[AROWS * 128];   // 16 KB f32 aggregate tile, XOR swizzle
  __shared__ float cntA[AROWS];
  const int g     = blockIdx.x & 63;
  const int slice = blockIdx.x >> 6;
  const int nodeBase = g * npg;
  const int vbase = slice * AROWS;
  const int t = threadIdx.x;
  float4* sA4 = (float4*)sA;
  const uint4* xb4 = (const uint4*)xbf;   // 16 uint4 per row

  // ---- phase A ----
  {
    const int gr = t >> 5, l32 = t & 31;
    const int lh = l32 & 15;           // uint4 slot within row
    const int half = l32 >> 4;         // 0: even edge, 1: odd edge
    const int* off = off_g + g * 1025;
    const int* el  = elist_g + g * EPG;
    #pragma unroll
    for (int ip = 0; ip < 4; ++ip) {
      const int vbA = gr * 8 + ip * 2, vbB = vbA + 1;
      const int vA = vbase + vbA, vB = vbase + vbB;
      float accA[8] = {0,0,0,0,0,0,0,0}, accB[8] = {0,0,0,0,0,0,0,0};
      int eA = 0, endA = 0, eB = 0, endB = 0;
      if (vA < npg) { eA = off[vA]; endA = off[vA + 1]; }
      if (vB < npg) { eB = off[vB]; endB = off[vB + 1]; }
      const int cnA = endA - eA, cnB = endB - eB;
      // 4 independent 512B loads in flight (2 per dest row)
      while (eA + 4 <= endA && eB + 4 <= endB) {
        int ia0 = el[eA + half],     ia1 = el[eA + 2 + half];
        int ib0 = el[eB + half],     ib1 = el[eB + 2 + half];
        uint4 ua0 = xb4[(size_t)ia0 * 16 + lh];
        uint4 ua1 = xb4[(size_t)ia1 * 16 + lh];
        uint4 ub0 = xb4[(size_t)ib0 * 16 + lh];
        uint4 ub1 = xb4[(size_t)ib1 * 16 + lh];
        add8(accA, ua0); add8(accA, ua1);
        add8(accB, ub0); add8(accB, ub1);
        eA += 4; eB += 4;
      }
      // drain A: pairs then single
      while (eA + 2 <= endA) {
        uint4 u = xb4[(size_t)el[eA + half] * 16 + lh];
        add8(accA, u);
        eA += 2;
      }
      if (eA < endA && half == 0) {
        uint4 u = xb4[(size_t)el[eA] * 16 + lh];
        add8(accA, u);
      }
      // drain B
      while (eB + 2 <= endB) {
        uint4 u = xb4[(size_t)el[eB + half] * 16 + lh];
        add8(accB, u);
        eB += 2;
      }
      if (eB < endB && half == 0) {
        uint4 u = xb4[(size_t)el[eB] * 16 + lh];
        add8(accB, u);
      }
      // merge even/odd halves
      #pragma unroll
      for (int j = 0; j < 8; ++j) {
        accA[j] += __shfl_xor(accA[j], 16);
        accB[j] += __shfl_xor(accB[j], 16);
      }
      if (half == 0) {
        float4 a0 = {accA[0], accA[1], accA[2], accA[3]};
        float4 a1 = {accA[4], accA[5], accA[6], accA[7]};
        float4 b0 = {accB[0], accB[1], accB[2], accB[3]};
        float4 b1 = {accB[4], accB[5], accB[6], accB[7]};
        sA4[vbA * 32 + ((2 * lh + 0) ^ (vbA & 7))] = a0;
        sA4[vbA * 32 + ((2 * lh + 1) ^ (vbA & 7))] = a1;
        sA4[vbB * 32 + ((2 * lh + 0) ^ (vbB & 7))] = b0;
        sA4[vbB * 32 + ((2 * lh + 1) ^ (vbB & 7))] = b1;
      }
      if (l32 == 0) { cntA[vbA] = (float)cnA; cntA[vbB] = (float)cnB; }
    }
  }
  __syncthreads();

  // ---- phase B: MFMA GEMM (2 waves x 16 rows) ----
  const int wv = t >> 6, l = t & 63;
  const int lrow = l & 15, lk = l >> 4;      // lk 0..3
  const int rb = wv * 16;
  const int rowb = rb + lrow;                // 0..31
  const int rsw = rowb & 7;
  const int rowg = nodeBase + min(vbase + rowb, npg - 1);
  const float invc = 1.0f / fmaxf(cntA[rowb], 1.0f);
  f32x4 acc[8];
  #pragma unroll
  for (int nt = 0; nt < 8; ++nt) acc[nt] = (f32x4){0.f, 0.f, 0.f, 0.f};
  const float4* sArow = sA4 + rowb * 32;
  const uint4* xrow4 = (const uint4*)xbf + (size_t)rowg * 16;   // 16 uint4/row
  const short8v* bh = (const short8v*)whiF;
  const short8v* bo = (const short8v*)wloF;

  #pragma unroll
  for (int kk = 0; kk < 8; ++kk) {
    short8v ahi, alo;
    bool self16 = (kk >= 4);     // self term is exactly bf16 -> skip alo
    if (!self16) {
      int sbase = kk * 8 + lk * 2;
      float4 a0 = sArow[(sbase + 0) ^ rsw];
      float4 a1 = sArow[(sbase + 1) ^ rsw];
      float av[8] = { a0.x * invc, a0.y * invc, a0.z * invc, a0.w * invc,
                      a1.x * invc, a1.y * invc, a1.z * invc, a1.w * invc };
      #pragma unroll
      for (int j = 0; j < 8; ++j) {
        unsigned hb2 = bf16rne(av[j]);
        float hif = __uint_as_float(hb2 << 16);
        ahi[j] = (short)hb2;
        alo[j] = (short)bf16rne(av[j] - hif);
      }
    } else {
      uint4 u = xrow4[(kk - 4) * 4 + lk];
      ahi[0] = (short)(u.x & 0xffff); ahi[1] = (short)(u.x >> 16);
      ahi[2] = (short)(u.y & 0xffff); ahi[3] = (short)(u.y >> 16);
      ahi[4] = (short)(u.z & 0xffff); ahi[5] = (short)(u.z >> 16);
      ahi[6] = (short)(u.w & 0xffff); ahi[7] = (short)(u.w >> 16);
    }
    #pragma unroll
    for (int nt = 0; nt < 8; ++nt) {
      int fi = (kk * 8 + nt) * 64 + l;
      short8v bhi = bh[fi];
      short8v blo = bo[fi];
      acc[nt] = __builtin_amdgcn_mfma_f32_16x16x32_bf16(ahi, bhi, acc[nt], 0, 0, 0);
      if (!self16)
        acc[nt] = __builtin_amdgcn_mfma_f32_16x16x32_bf16(alo, bhi, acc[nt], 0, 0, 0);
      acc[nt] = __builtin_amdgcn_mfma_f32_16x16x32_bf16(ahi, blo, acc[nt], 0, 0, 0);
    }
  }

  float sp0 = 0.f, sp1 = 0.f, sp2 = 0.f, sp3 = 0.f;
  const int mbv = vbase + rb + lk * 4;
  #pragma unroll
  for (int nt = 0; nt < 8; ++nt) {
    int col = nt * 16 + lrow;
    float bb = bl[col], pv = pw[col];
    float h0 = fmaxf(acc[nt][0] + bb, 0.f);
    float h1 = fmaxf(acc[nt][1] + bb, 0.f);
    float h2 = fmaxf(acc[nt][2] + bb, 0.f);
    float h3 = fmaxf(acc[nt][3] + bb, 0.f);
    if (mbv + 0 < npg) hbf[(size_t)(nodeBase + mbv + 0) * DIM + col] = (unsigned short)bf16rne(h0);
    if (mbv + 1 < npg) hbf[(size_t)(nodeBase + mbv + 1) * DIM + col] = (unsigned short)bf16rne(h1);
    if (mbv + 2 < npg) hbf[(size_t)(nodeBase + mbv + 2) * DIM + col] = (unsigned short)bf16rne(h2);
    if (mbv + 3 < npg) hbf[(size_t)(nodeBase + mbv + 3) * DIM + col] = (unsigned short)bf16rne(h3);
    sp0 += h0 * pv; sp1 += h1 * pv; sp2 += h2 * pv; sp3 += h3 * pv;
  }
  #pragma unroll
  for (int off = 1; off <= 8; off <<= 1) {
    sp0 += __shfl_xor(sp0, off);
    sp1 += __shfl_xor(sp1, off);
    sp2 += __shfl_xor(sp2, off);
    sp3 += __shfl_xor(sp3, off);
  }
  if (lrow == 0) {
    if (mbv + 0 < npg) score[nodeBase + mbv + 0] = sp0;
    if (mbv + 1 < npg) score[nodeBase + mbv + 1] = sp1;
    if (mbv + 2 < npg) score[nodeBase + mbv + 2] = sp2;
    if (mbv + 3 < npg) score[nodeBase + mbv + 3] = sp3;
  }
}

// ------- fused: shuffle-bitonic top-k + relabel + build next CSR ----------
__global__ __launch_bounds__(1024) void k_topk_fused(
    const float* __restrict__ score, const float* __restrict__ inv_norm_p,
    int npg, int k, int* __restrict__ sel_pos, float* __restrict__ sel_scale,
    int build_next, int write_eout,
    const int* __restrict__ ein_src, const int* __restrict__ ein_dst,
    int* __restrict__ eout_src, int* __restrict__ eout_dst,
    int* __restrict__ off_g, int* __restrict__ elist_g, float* __restrict__ c_out)
{
  __shared__ float key[1024];
  __shared__ int   idxs[1024];
  __shared__ int   nid[1024];
  __shared__ int   cnt[1024];
  __shared__ int   cur[1024];
  __shared__ int   wsum[16];
  const int t = threadIdx.x, g = blockIdx.x;
  const int base = g * npg;
  float rk = (t < npg) ? score[base + t] : -3.402823466e38f;
  int   ri = t;
  nid[t] = -1;
  cnt[t] = 0;

  #pragma unroll
  for (int size = 2; size <= 1024; size <<= 1) {
    for (int stride = size >> 1; stride >= 64; stride >>= 1) {
      key[t] = rk; idxs[t] = ri;
      __syncthreads();
      float km = key[t ^ stride];
      int   im = idxs[t ^ stride];
      __syncthreads();
      bool mf = (rk > km) || (rk == km && ri < im);
      bool desc = ((t & size) == 0);
      bool lower = ((t & stride) == 0);
      bool keep = desc ? (lower ? mf : !mf) : (lower ? !mf : mf);
      if (!keep) { rk = km; ri = im; }
    }
    for (int stride = (size >> 1) > 32 ? 32 : (size >> 1); stride >= 1; stride >>= 1) {
      float km = __shfl_xor(rk, stride);
      int   im = __shfl_xor(ri, stride);
      bool mf = (rk > km) || (rk == km && ri < im);
      bool desc = ((t & size) == 0);
      bool lower = ((t & stride) == 0);
      bool keep = desc ? (lower ? mf : !mf) : (lower ? !mf : mf);
      if (!keep) { rk = km; ri = im; }
    }
  }

  if (t < k) {
    float inv = *inv_norm_p;
    nid[ri] = t;
    sel_pos[g * k + t] = base + ri;
    sel_scale[g * k + t] = tanhf(rk * inv);
  }
  if (!build_next) return;
  __syncthreads();
  const int e0 = g * EPG;
  const int newBase = g * k;
  int lns[8], lnd[8];
  #pragma unroll
  for (int i = 0; i < 8; ++i) {
    int e = e0 + t + i * 1024;
    int sv = ein_src[e];
    int ns = -1, nd = -1;
    if (sv >= 0) {
      int dv = ein_dst[e];
      ns = nid[sv - base];
      nd = nid[dv - base];
      if (ns < 0 || nd < 0) ns = -1;
    }
    lns[i] = ns; lnd[i] = nd;
    if (write_eout) {
      eout_src[e] = (ns >= 0) ? (newBase + ns) : -1;
      eout_dst[e] = (ns >= 0) ? (newBase + nd) : -1;
    }
    if (ns >= 0) atomicAdd(&cnt[nd], 1);
  }
  __syncthreads();
  const int lane = t & 63, w = t >> 6;
  int cv = cnt[t];
  int x = cv;
  #pragma unroll
  for (int off = 1; off < 64; off <<= 1) {
    int y = __shfl_up(x, off);
    if (lane >= off) x += y;
  }
  if (lane == 63) wsum[w] = x;
  __syncthreads();
  if (t < 16) {
    int v = wsum[t];
    #pragma unroll
    for (int off2 = 1; off2 < 16; off2 <<= 1) {
      int y = __shfl_up(v, off2);
      if (t >= off2) v += y;
    }
    wsum[t] = v;
  }
  __syncthreads();
  int incl = x + (w ? wsum[w - 1] : 0);
  int excl = incl - cv;
  cur[t] = excl;
  off_g[g * 1025 + t] = excl;
  if (t < k) c_out[newBase + t] = (float)cv;
  __syncthreads();
  int* elp = elist_g + g * EPG;
  #pragma unroll
  for (int i = 0; i < 8; ++i) {
    if (lns[i] >= 0) {
      int pos = atomicAdd(&cur[lnd[i]], 1);
      elp[pos] = newBase + lns[i];
    }
  }
}

// ------- fused pool + readout partial (bf16 rows): block=(graph,chunk) ----
__global__ __launch_bounds__(256) void k_pool_part(const unsigned short* __restrict__ hbf,
    const int* __restrict__ sel_pos, const float* __restrict__ sel_scale, int k,
    unsigned short* __restrict__ xbf, float* __restrict__ pmax, float* __restrict__ psum)
{
  __shared__ float4 smx[256], ssm[256];
  const int b  = blockIdx.x >> 4;
  const int ch = blockIdx.x & (RCHUNK - 1);
  const int rpc = (k + RCHUNK - 1) / RCHUNK;
  const int r0 = ch * rpc;
  const int r1 = min(k, r0 + rpc);
  const int d4  = threadIdx.x & 31;
  const int sub = threadIdx.x >> 5;
  const float NEG = -3.402823466e38f;
  const uint2* hb2 = (const uint2*)hbf;
  uint2* xb2 = (uint2*)xbf;
  float4 mx = {NEG, NEG, NEG, NEG};
  float4 sm = {0.f, 0.f, 0.f, 0.f};
  for (int r = r0 + sub; r < r1; r += 8) {
    int j = b * k + r;
    float scv = sel_scale[j];
    uint2 u = hb2[(size_t)sel_pos[j] * 32 + d4];
    float4 v;
    v.x = bf_lo(u.x) * scv; v.y = bf_hi(u.x) * scv;
    v.z = bf_lo(u.y) * scv; v.w = bf_hi(u.y) * scv;
    uint2 o;
    o.x = pack2bf(v.x, v.y);
    o.y = pack2bf(v.z, v.w);
    xb2[(size_t)j * 32 + d4] = o;
    v.x = bf_lo(o.x); v.y = bf_hi(o.x); v.z = bf_lo(o.y); v.w = bf_hi(o.y);
    mx.x = fmaxf(mx.x, v.x); mx.y = fmaxf(mx.y, v.y);
    mx.z = fmaxf(mx.z, v.z); mx.w = fmaxf(mx.w, v.w);
    sm.x += v.x; sm.y += v.y; sm.z += v.z; sm.w += v.w;
  }
  smx[threadIdx.x] = mx; ssm[threadIdx.x] = sm;
  __syncthreads();
  if (sub < 4) {
    #pragma unroll
    for (int step = 4; step >= 1; step >>= 1) {
      if (sub < step) {
        float4 m2 = smx[(sub + step) * 32 + d4];
        float4 s2 = ssm[(sub + step) * 32 + d4];
        mx = smx[sub * 32 + d4]; sm = ssm[sub * 32 + d4];
        mx.x = fmaxf(mx.x, m2.x); mx.y = fmaxf(mx.y, m2.y);
        mx.z = fmaxf(mx.z, m2.z); mx.w = fmaxf(mx.w, m2.w);
        sm.x += s2.x; sm.y += s2.y; sm.z += s2.z; sm.w += s2.w;
        smx[sub * 32 + d4] = mx; ssm[sub * 32 + d4] = sm;
      }
      __syncthreads();
    }
  }
  if (sub == 0) {
    int o = (b * RCHUNK + ch) * 32 + d4;
    ((float4*)pmax)[o] = smx[d4];
    ((float4*)psum)[o] = ssm[d4];
  }
}

// ------- merged readout: combine all 3 stages' partials into rdT ----------
__global__ __launch_bounds__(128) void k_readout_final3(
    const float* __restrict__ pmax, const float* __restrict__ psum,
    int k0, int k1, int k2, float* __restrict__ rdT)
{
  int b = blockIdx.x, d = threadIdx.x;
  const int ks[3] = {k0, k1, k2};
  float tmx = 0.f, tmn = 0.f;
  #pragma unroll
  for (int s = 0; s < 3; ++s) {
    const float* pm = pmax + (size_t)s * PSTRIDE;
    const float* ps = psum + (size_t)s * PSTRIDE;
    float mx = -3.402823466e38f, sm = 0.f;
    #pragma unroll
    for (int c = 0; c < RCHUNK; ++c) {
      int o = (b * RCHUNK + c) * 128 + d;
      mx = fmaxf(mx, pm[o]);
      sm += ps[o];
    }
    tmx += mx;
    tmn += sm / (float)ks[s];
  }
  rdT[d * 64 + b] = tmx;
  rdT[(128 + d) * 64 + b] = tmn;
}

// ------- MLP fc1 + BN1 + relu: 16 blocks, lane=graph, wave=feature --------
__global__ __launch_bounds__(512) void k_mlp_fc1(const float* __restrict__ rdT,
    const float* __restrict__ fc1_w, const float* __restrict__ fc1_b,
    const float* __restrict__ g1, const float* __restrict__ be1,
    float* __restrict__ y1n)
{
  __shared__ float W[8 * 256];
  __shared__ float R[256 * 64];
  const int t = threadIdx.x, b = blockIdx.x;
  ((float4*)W)[t] = ((const float4*)(fc1_w + (size_t)b * 8 * 256))[t];
  #pragma unroll
  for (int i = 0; i < 8; ++i)
    ((float4*)R)[t + i * 512] = ((const float4*)rdT)[t + i * 512];
  __syncthreads();
  const int g = t & 63, w = t >> 6;
  const float* wrow = W + w * 256;
  float acc = 0.f;
  #pragma unroll 4
  for (int k = 0; k < 256; ++k) acc += R[k * 64 + g] * wrow[k];
  int f = b * 8 + w;
  float y = acc + fc1_b[f];
  float s = y, s2 = y * y;
  #pragma unroll
  for (int off = 32; off; off >>= 1) {
    s  += __shfl_xor(s,  off);
    s2 += __shfl_xor(s2, off);
  }
  float mu = s * 0.015625f;
  float var = s2 * 0.015625f - mu * mu;
  float inv = 1.0f / sqrtf(var + 1e-5f);
  y1n[f * 64 + g] = fmaxf((y - mu) * inv * g1[f] + be1[f], 0.f);
}

// ------- MLP rest: fc2 + BN2 + relu + lin + sigmoid (1 block) -------------
__global__ __launch_bounds__(1024) void k_mlp_rest(const float* __restrict__ y1n,
    const float* __restrict__ fc2_w, const float* __restrict__ fc2_b,
    const float* __restrict__ g2, const float* __restrict__ be2,
    const float* __restrict__ lin_w, const float* __restrict__ lin_b,
    float* __restrict__ out)
{
  __shared__ float W2[64 * 128];
  __shared__ float Y[128 * 64];
  __shared__ float part[16 * 64];
  const int t = threadIdx.x;
  #pragma unroll
  for (int i = 0; i < 2; ++i) {
    ((float4*)W2)[t + i * 1024] = ((const float4*)fc2_w)[t + i * 1024];
    ((float4*)Y) [t + i * 1024] = ((const float4*)y1n)[t + i * 1024];
  }
  __syncthreads();
  const int g = t & 63, w = t >> 6;
  float acc2[4] = {0.f, 0.f, 0.f, 0.f};
  const float* w20 = W2 + (w * 4 + 0) * 128;
  const float* w21 = W2 + (w * 4 + 1) * 128;
  const float* w22 = W2 + (w * 4 + 2) * 128;
  const float* w23 = W2 + (w * 4 + 3) * 128;
  #pragma unroll 4
  for (int k = 0; k < 128; ++k) {
    float yv = Y[k * 64 + g];
    acc2[0] += yv * w20[k];
    acc2[1] += yv * w21[k];
    acc2[2] += yv * w22[k];
    acc2[3] += yv * w23[k];
  }
  float pp = 0.f;
  #pragma unroll
  for (int j = 0; j < 4; ++j) {
    int m = w * 4 + j;
    float y = acc2[j] + fc2_b[m];
    float s = y, s2 = y * y;
    #pragma unroll
    for (int off = 32; off; off >>= 1) {
      s  += __shfl_xor(s,  off);
      s2 += __shfl_xor(s2, off);
    }
    float mu = s * 0.015625f;
    float var = s2 * 0.015625f - mu * mu;
    float inv = 1.0f / sqrtf(var + 1e-5f);
    float yn = fmaxf((y - mu) * inv * g2[m] + be2[m], 0.f);
    pp += yn * lin_w[m];
  }
  part[w * 64 + g] = pp;
  __syncthreads();
  if (w == 0) {
    float a = lin_b[0];
    #pragma unroll
    for (int c = 0; c < 16; ++c) a += part[c * 64 + g];
    out[g] = 1.0f / (1.0f + expf(-a));
  }
}

extern "C" void kernel_launch(void* const* d_in, const int* in_sizes, int n_in,
                              void* d_out, int out_size, void* d_ws, size_t ws_size,
                              hipStream_t stream) {
  const int*   node_idx = (const int*)  d_in[0];
  const int*   edge_idx = (const int*)  d_in[1];
  const float* emb      = (const float*)d_in[2];
  const float* w1l      = (const float*)d_in[3];
  const float* b1l      = (const float*)d_in[4];
  const float* w1r      = (const float*)d_in[5];
  const float* pool_w   = (const float*)d_in[6];
  const float* w2l      = (const float*)d_in[7];
  const float* b2l      = (const float*)d_in[8];
  const float* w2r      = (const float*)d_in[9];
  const float* fc1_w    = (const float*)d_in[10];
  const float* fc1_b    = (const float*)d_in[11];
  const float* bn1_g    = (const float*)d_in[12];
  const float* bn1_b    = (const float*)d_in[13];
  const float* fc2_w    = (const float*)d_in[14];
  const float* fc2_b    = (const float*)d_in[15];
  const float* bn2_g    = (const float*)d_in[16];
  const float* bn2_b    = (const float*)d_in[17];
  const float* lin_w    = (const float*)d_in[18];
  const float* lin_b    = (const float*)d_in[19];
  float* out = (float*)d_out;

  char* p = (char*)d_ws;
  auto alloc = [&](size_t bytes) -> void* {
    void* r = (void*)p;
    p += (bytes + 255) & ~(size_t)255;
    return r;
  };
  unsigned short* x_bf = (unsigned short*)alloc((size_t)NNODE * DIM * 2);
  unsigned short* h_bf = (unsigned short*)alloc((size_t)NNODE * DIM * 2);
  float* c_buf     = (float*)alloc((size_t)NNODE * 4);
  float* score     = (float*)alloc((size_t)NNODE * 4);
  int*   sel_pos   = (int*)  alloc((size_t)NGRAPH * 820 * 4);
  float* sel_scale = (float*)alloc((size_t)NGRAPH * 820 * 4);
  int*   src_cur   = (int*)  alloc((size_t)NEDGE * 4);
  int*   dst_cur   = (int*)  alloc((size_t)NEDGE * 4);
  int*   off_g     = (int*)  alloc((size_t)NGRAPH * 1025 * 4);
  int*   elist_g   = (int*)  alloc((size_t)NGRAPH * EPG * 4);
  float* rdT       = (float*)alloc((size_t)256 * 64 * 4);
  short* whiF      = (short*)alloc((size_t)2 * 32768 * 2);
  short* wloF      = (short*)alloc((size_t)2 * 32768 * 2);
  float* y1n       = (float*)alloc((size_t)128 * 64 * 4);
  float* pmax      = (float*)alloc(PSTRIDE * 3 * 4);
  float* psum      = (float*)alloc(PSTRIDE * 3 * 4);
  float* inv_norm  = (float*)alloc(256);

  k_gather<<<NNODE * 32 / 256, 256, 0, stream>>>(emb, node_idx, x_bf);
  k_norm<<<1, 64, 0, stream>>>(pool_w, inv_norm);
  k_prep_wfrag<<<256, 256, 0, stream>>>(w1l, w1r, w2l, w2r, whiF, wloF);
  k_csr0<<<NGRAPH, 1024, 0, stream>>>(edge_idx, off_g, elist_g, c_buf);

  const int Ks[3] = {820, 656, 525};
  int npg = NPG0;
  for (int stage = 0; stage < 3; ++stage) {
    const short* whi_s = whiF + (stage ? 32768 : 0);
    const short* wlo_s = wloF + (stage ? 32768 : 0);
    const float* bl    = stage ? b2l : b1l;
    int k = Ks[stage];
    int slices = (npg + AROWS - 1) / AROWS;

    k_agg_gemm<<<slices * 64, 128, 0, stream>>>(off_g, elist_g, x_bf, h_bf,
                                                whi_s, wlo_s, bl, pool_w,
                                                score, npg);
    const int* ein_s = (stage == 0) ? edge_idx          : src_cur;
    const int* ein_d = (stage == 0) ? (edge_idx + NEDGE) : dst_cur;
    k_topk_fused<<<NGRAPH, 1024, 0, stream>>>(score, inv_norm, npg, k,
        sel_pos, sel_scale,
        (stage < 2) ? 1 : 0, (stage == 0) ? 1 : 0,
        ein_s, ein_d, src_cur, dst_cur,
        off_g, elist_g, c_buf);
    k_pool_part<<<NGRAPH * RCHUNK, 256, 0, stream>>>(h_bf, sel_pos, sel_scale, k,
        x_bf, pmax + (size_t)stage * PSTRIDE, psum + (size_t)stage * PSTRIDE);
    npg = k;
  }

  k_readout_final3<<<NGRAPH, 128, 0, stream>>>(pmax, psum, Ks[0], Ks[1], Ks[2], rdT);
  k_mlp_fc1<<<16, 512, 0, stream>>>(rdT, fc1_w, fc1_b, bn1_g, bn1_b, y1n);
  k_mlp_rest<<<1, 1024, 0, stream>>>(y1n, fc2_w, fc2_b, bn2_g, bn2_b,
                                     lin_w, lin_b, out);
}